// Round 1
// baseline (6571.420 us; speedup 1.0000x reference)
//
#include <hip/hip_runtime.h>

#define N_NODES  100000
#define N_EDGES  3200000
#define N_GRAPHS 64

// ---------------- degree / normalization ----------------
__global__ void k_degree(const int* __restrict__ dst, int* __restrict__ cnt, int E) {
    int i = blockIdx.x * blockDim.x + threadIdx.x;
    if (i < E) atomicAdd(&cnt[dst[i]], 1);
}

__global__ void k_dinv(const int* __restrict__ cnt, float* __restrict__ dinv, int N) {
    int i = blockIdx.x * blockDim.x + threadIdx.x;
    if (i < N) dinv[i] = 1.0f / sqrtf((float)(cnt[i] + 1));  // +1 self-loop; deg>=1 always
}

// ---------------- H1 = x @ W1  (x: [N,3], W1: [3,64]) ----------------
// one wave per node: lane f computes feature f. x reads broadcast, W1 coalesced.
__global__ void k_xW1(const float* __restrict__ x, const float* __restrict__ W1,
                      float* __restrict__ A, int N) {
    int tid = blockIdx.x * blockDim.x + threadIdx.x;
    int n = tid >> 6, f = tid & 63;
    if (n >= N) return;
    float x0 = x[n * 3 + 0], x1 = x[n * 3 + 1], x2 = x[n * 3 + 2];
    A[tid] = x0 * W1[f] + x1 * W1[64 + f] + x2 * W1[128 + f];
}

// ---------------- AGG init with self-loop term: AGG[n] = dinv[n]^2 * H[n] ----------------
__global__ void k_selfinit(const float* __restrict__ H, const float* __restrict__ dinv,
                           float* __restrict__ AGG, int N) {
    int tid = blockIdx.x * blockDim.x + threadIdx.x;
    int n = tid >> 4, q = tid & 15;
    if (n >= N) return;
    float w = dinv[n] * dinv[n];
    float4 h = ((const float4*)H)[(size_t)n * 16 + q];
    float4 o = make_float4(w * h.x, w * h.y, w * h.z, w * h.w);
    ((float4*)AGG)[(size_t)n * 16 + q] = o;
}

// ---------------- edge scatter: AGG[dst] += dinv[src]*dinv[dst] * H[src] ----------------
// 16 lanes per edge, float4 gather, 4 fp32 atomics per lane.
__global__ void k_scatter(const float* __restrict__ H, const int* __restrict__ src,
                          const int* __restrict__ dst, const float* __restrict__ dinv,
                          float* __restrict__ AGG, int E) {
    int tid = blockIdx.x * blockDim.x + threadIdx.x;
    int e = tid >> 4, q = tid & 15;
    if (e >= E) return;
    int s = src[e], d = dst[e];
    float w = dinv[s] * dinv[d];
    float4 h = ((const float4*)(H + (size_t)s * 64))[q];
    float* out = AGG + (size_t)d * 64 + (size_t)q * 4;
    atomicAdd(out + 0, w * h.x);
    atomicAdd(out + 1, w * h.y);
    atomicAdd(out + 2, w * h.z);
    atomicAdd(out + 3, w * h.w);
}

// ---------------- T = relu(AGG + b) @ W2 -> out  (wave per node, W2 staged in LDS) ----------------
__global__ __launch_bounds__(256) void k_biasrelu_mm(
        const float* __restrict__ AGG, const float* __restrict__ b,
        const float* __restrict__ W2, float* __restrict__ out, int N) {
    __shared__ float W2s[64 * 64];
    for (int i = threadIdx.x; i < 64 * 64; i += 256) W2s[i] = W2[i];
    __syncthreads();
    int tid = blockIdx.x * blockDim.x + threadIdx.x;
    int n = tid >> 6, f = tid & 63;
    if (n >= N) return;
    float r = fmaxf(AGG[(size_t)n * 64 + f] + b[f], 0.0f);
    float acc = 0.0f;
#pragma unroll 16
    for (int k = 0; k < 64; ++k) {
        float rk = __shfl(r, k);           // wave64: broadcast lane k's relu'd value
        acc += rk * W2s[k * 64 + f];       // lanes hit banks f%32 -> 2-way alias, free
    }
    out[(size_t)n * 64 + f] = acc;
}

// ---------------- pool: s[n]=dot(relu(AGG+b2),Wr); segment-sum into gsum/gcnt ----------------
__global__ void k_pool(const float* __restrict__ AGG, const float* __restrict__ b2,
                       const float* __restrict__ Wr, const int* __restrict__ batch,
                       float* __restrict__ gsum, float* __restrict__ gcnt, int N) {
    int tid = blockIdx.x * blockDim.x + threadIdx.x;
    int n = tid >> 6, f = tid & 63;
    if (n >= N) return;
    float r = fmaxf(AGG[(size_t)n * 64 + f] + b2[f], 0.0f) * Wr[f];
    for (int off = 32; off > 0; off >>= 1) r += __shfl_down(r, off);
    if (f == 0) {
        int g = batch[n];
        atomicAdd(&gsum[g], r);
        atomicAdd(&gcnt[g], 1.0f);
    }
}

__global__ void k_out(const float* __restrict__ gsum, const float* __restrict__ gcnt,
                      const float* __restrict__ br, float* __restrict__ out) {
    int g = threadIdx.x;
    if (g < N_GRAPHS) out[g] = gsum[g] / fmaxf(gcnt[g], 1.0f) + br[0];
}

extern "C" void kernel_launch(void* const* d_in, const int* in_sizes, int n_in,
                              void* d_out, int out_size, void* d_ws, size_t ws_size,
                              hipStream_t stream) {
    const float* x     = (const float*)d_in[0];
    const int*   ei    = (const int*)d_in[1];   // [2, E] row-major (int32 per harness)
    const int*   batch = (const int*)d_in[2];
    const float* W1    = (const float*)d_in[3];
    const float* b1    = (const float*)d_in[4];
    const float* W2    = (const float*)d_in[5];
    const float* b2    = (const float*)d_in[6];
    const float* Wr    = (const float*)d_in[7];
    const float* br    = (const float*)d_in[8];
    float* out = (float*)d_out;

    const int N = N_NODES, E = N_EDGES;
    const int* src = ei;       // edge_index[0] = message sources
    const int* dst = ei + E;   // edge_index[1] = aggregation targets

    // workspace layout (~52 MB)
    char* w = (char*)d_ws;
    float* A    = (float*)w; w += (size_t)N * 64 * sizeof(float);
    float* B    = (float*)w; w += (size_t)N * 64 * sizeof(float);
    float* dinv = (float*)w; w += (size_t)N * sizeof(float);
    int*   cnt  = (int*)w;   w += (size_t)N * sizeof(int);
    float* gsum = (float*)w; w += N_GRAPHS * sizeof(float);
    float* gcnt = (float*)w; w += N_GRAPHS * sizeof(float);

    hipMemsetAsync(cnt,  0, (size_t)N * sizeof(int), stream);
    hipMemsetAsync(gsum, 0, N_GRAPHS * sizeof(float), stream);
    hipMemsetAsync(gcnt, 0, N_GRAPHS * sizeof(float), stream);

    k_degree<<<(E + 255) / 256, 256, 0, stream>>>(dst, cnt, E);
    k_dinv<<<(N + 255) / 256, 256, 0, stream>>>(cnt, dinv, N);

    // layer 1
    k_xW1<<<(N * 64) / 256, 256, 0, stream>>>(x, W1, A, N);
    k_selfinit<<<(N * 16 + 255) / 256, 256, 0, stream>>>(A, dinv, B, N);
    k_scatter<<<((size_t)E * 16) / 256, 256, 0, stream>>>(A, src, dst, dinv, B, E);

    // layer 2 input: relu(B + b1) @ W2 -> A
    k_biasrelu_mm<<<(N * 64) / 256, 256, 0, stream>>>(B, b1, W2, A, N);
    k_selfinit<<<(N * 16 + 255) / 256, 256, 0, stream>>>(A, dinv, B, N);
    k_scatter<<<((size_t)E * 16) / 256, 256, 0, stream>>>(A, src, dst, dinv, B, E);

    // pool + readout
    k_pool<<<(N * 64) / 256, 256, 0, stream>>>(B, b2, Wr, batch, gsum, gcnt, N);
    k_out<<<1, 64, 0, stream>>>(gsum, gcnt, br, out);
}

// Round 2
// 1634.336 us; speedup vs baseline: 4.0209x; 4.0209x over previous
//
#include <hip/hip_runtime.h>

#define N_NODES  100000
#define N_EDGES  3200000
#define N_GRAPHS 64
#define SCAN_BLOCK 1024

// ---------------- degree histogram (in-degree by dst, no self-loop) ----------------
__global__ void k_degree(const int* __restrict__ dst, int* __restrict__ cnt, int E) {
    int i = blockIdx.x * blockDim.x + threadIdx.x;
    if (i < E) atomicAdd(&cnt[dst[i]], 1);
}

__global__ void k_dinv(const int* __restrict__ cnt, float* __restrict__ dinv, int N) {
    int i = blockIdx.x * blockDim.x + threadIdx.x;
    if (i < N) dinv[i] = 1.0f / sqrtf((float)(cnt[i] + 1));  // +1 self-loop
}

// ---------------- exclusive scan of cnt -> rowptr (3 kernels) ----------------
__global__ void k_scan1(const int* __restrict__ cnt, int* __restrict__ rowptr,
                        int* __restrict__ bsum, int N) {
    __shared__ int tmp[SCAN_BLOCK];
    int t = threadIdx.x, g = blockIdx.x * SCAN_BLOCK + t;
    int v = (g < N) ? cnt[g] : 0;
    tmp[t] = v;
    __syncthreads();
    for (int off = 1; off < SCAN_BLOCK; off <<= 1) {
        int add = (t >= off) ? tmp[t - off] : 0;
        __syncthreads();
        tmp[t] += add;
        __syncthreads();
    }
    if (g < N) rowptr[g] = tmp[t] - v;                 // exclusive within block
    if (t == SCAN_BLOCK - 1) bsum[blockIdx.x] = tmp[t]; // block total
}

__global__ void k_scan2(int* __restrict__ bsum, int nb) {  // one block of 128
    __shared__ int tmp[128];
    int t = threadIdx.x;
    int v = (t < nb) ? bsum[t] : 0;
    tmp[t] = v;
    __syncthreads();
    for (int off = 1; off < 128; off <<= 1) {
        int add = (t >= off) ? tmp[t - off] : 0;
        __syncthreads();
        tmp[t] += add;
        __syncthreads();
    }
    if (t < nb) bsum[t] = tmp[t] - v;  // exclusive block offsets
}

__global__ void k_scan3(int* __restrict__ rowptr, const int* __restrict__ bsum,
                        int* __restrict__ cur, int N, int E) {
    int g = blockIdx.x * blockDim.x + threadIdx.x;
    if (g < N) {
        int r = rowptr[g] + bsum[g / SCAN_BLOCK];
        rowptr[g] = r;
        cur[g] = r;
    }
    if (g == 0) rowptr[N] = E;
}

// ---------------- CSR fill: bucket edges by dst ----------------
__global__ void k_fill(const int* __restrict__ src, const int* __restrict__ dst,
                       int* __restrict__ cur, int* __restrict__ csr_src, int E) {
    int i = blockIdx.x * blockDim.x + threadIdx.x;
    if (i >= E) return;
    int pos = atomicAdd(&cur[dst[i]], 1);
    csr_src[pos] = src[i];
}

// ---------------- H1 = x @ W1  (x: [N,3], W1: [3,64]) ----------------
__global__ void k_xW1(const float* __restrict__ x, const float* __restrict__ W1,
                      float* __restrict__ A, int N) {
    int tid = blockIdx.x * blockDim.x + threadIdx.x;
    int n = tid >> 6, f = tid & 63;
    if (n >= N) return;
    float x0 = x[n * 3 + 0], x1 = x[n * 3 + 1], x2 = x[n * 3 + 2];
    A[tid] = x0 * W1[f] + x1 * W1[64 + f] + x2 * W1[128 + f];
}

// ---------------- CSR gather-aggregate: 16 lanes per node, float4 regs, no atomics ----
// out[n] = dinv[n]^2 * H[n] + sum_{s in in(n)} dinv[s]*dinv[n] * H[s]
__global__ __launch_bounds__(256) void k_agg(
        const float* __restrict__ H, const int* __restrict__ csr_src,
        const int* __restrict__ rowptr, const float* __restrict__ dinv,
        float* __restrict__ out, int N) {
    int tid = blockIdx.x * blockDim.x + threadIdx.x;
    int n = tid >> 4, q = tid & 15;
    if (n >= N) return;
    int beg = rowptr[n], end = rowptr[n + 1];
    float dn = dinv[n];
    float4 acc = make_float4(0.f, 0.f, 0.f, 0.f);
    for (int i = beg; i < end; ++i) {
        int s = csr_src[i];                       // uniform across the 16-lane group
        float w = dinv[s] * dn;
        float4 h = ((const float4*)(H + (size_t)s * 64))[q];
        acc.x += w * h.x; acc.y += w * h.y; acc.z += w * h.z; acc.w += w * h.w;
    }
    float ws = dn * dn;                           // self-loop
    float4 h = ((const float4*)(H + (size_t)n * 64))[q];
    acc.x += ws * h.x; acc.y += ws * h.y; acc.z += ws * h.z; acc.w += ws * h.w;
    ((float4*)(out + (size_t)n * 64))[q] = acc;
}

// ---------------- T = relu(AGG + b) @ W2 (wave per node, W2 in LDS) ----------------
__global__ __launch_bounds__(256) void k_biasrelu_mm(
        const float* __restrict__ AGG, const float* __restrict__ b,
        const float* __restrict__ W2, float* __restrict__ out, int N) {
    __shared__ float W2s[64 * 64];
    for (int i = threadIdx.x; i < 64 * 64; i += 256) W2s[i] = W2[i];
    __syncthreads();
    int tid = blockIdx.x * blockDim.x + threadIdx.x;
    int n = tid >> 6, f = tid & 63;
    if (n >= N) return;
    float r = fmaxf(AGG[(size_t)n * 64 + f] + b[f], 0.0f);
    float acc = 0.0f;
#pragma unroll 16
    for (int k = 0; k < 64; ++k) {
        float rk = __shfl(r, k);
        acc += rk * W2s[k * 64 + f];
    }
    out[(size_t)n * 64 + f] = acc;
}

// ---------------- pool: s[n]=dot(relu(AGG+b2),Wr); segment-sum ----------------
__global__ void k_pool(const float* __restrict__ AGG, const float* __restrict__ b2,
                       const float* __restrict__ Wr, const int* __restrict__ batch,
                       float* __restrict__ gsum, float* __restrict__ gcnt, int N) {
    int tid = blockIdx.x * blockDim.x + threadIdx.x;
    int n = tid >> 6, f = tid & 63;
    if (n >= N) return;
    float r = fmaxf(AGG[(size_t)n * 64 + f] + b2[f], 0.0f) * Wr[f];
    for (int off = 32; off > 0; off >>= 1) r += __shfl_down(r, off);
    if (f == 0) {
        int g = batch[n];
        atomicAdd(&gsum[g], r);
        atomicAdd(&gcnt[g], 1.0f);
    }
}

__global__ void k_out(const float* __restrict__ gsum, const float* __restrict__ gcnt,
                      const float* __restrict__ br, float* __restrict__ out) {
    int g = threadIdx.x;
    if (g < N_GRAPHS) out[g] = gsum[g] / fmaxf(gcnt[g], 1.0f) + br[0];
}

extern "C" void kernel_launch(void* const* d_in, const int* in_sizes, int n_in,
                              void* d_out, int out_size, void* d_ws, size_t ws_size,
                              hipStream_t stream) {
    const float* x     = (const float*)d_in[0];
    const int*   ei    = (const int*)d_in[1];   // [2, E]
    const int*   batch = (const int*)d_in[2];
    const float* W1    = (const float*)d_in[3];
    const float* b1    = (const float*)d_in[4];
    const float* W2    = (const float*)d_in[5];
    const float* b2    = (const float*)d_in[6];
    const float* Wr    = (const float*)d_in[7];
    const float* br    = (const float*)d_in[8];
    float* out = (float*)d_out;

    const int N = N_NODES, E = N_EDGES;
    const int NB = (N + SCAN_BLOCK - 1) / SCAN_BLOCK;  // 98
    const int* src = ei;
    const int* dst = ei + E;

    // workspace (~65 MB)
    char* w = (char*)d_ws;
    float* A       = (float*)w; w += (size_t)N * 64 * sizeof(float);
    float* B       = (float*)w; w += (size_t)N * 64 * sizeof(float);
    int*   csr_src = (int*)w;   w += (size_t)E * sizeof(int);
    float* dinv    = (float*)w; w += (size_t)N * sizeof(float);
    int*   cnt     = (int*)w;   w += (size_t)N * sizeof(int);
    int*   rowptr  = (int*)w;   w += (size_t)(N + 1) * sizeof(int);
    int*   cur     = (int*)w;   w += (size_t)N * sizeof(int);
    int*   bsum    = (int*)w;   w += 128 * sizeof(int);
    float* gsum    = (float*)w; w += N_GRAPHS * sizeof(float);
    float* gcnt    = (float*)w; w += N_GRAPHS * sizeof(float);

    hipMemsetAsync(cnt,  0, (size_t)N * sizeof(int), stream);
    hipMemsetAsync(gsum, 0, N_GRAPHS * sizeof(float), stream);
    hipMemsetAsync(gcnt, 0, N_GRAPHS * sizeof(float), stream);

    // CSR build
    k_degree<<<(E + 255) / 256, 256, 0, stream>>>(dst, cnt, E);
    k_dinv<<<(N + 255) / 256, 256, 0, stream>>>(cnt, dinv, N);
    k_scan1<<<NB, SCAN_BLOCK, 0, stream>>>(cnt, rowptr, bsum, N);
    k_scan2<<<1, 128, 0, stream>>>(bsum, NB);
    k_scan3<<<(N + 255) / 256, 256, 0, stream>>>(rowptr, bsum, cur, N, E);
    k_fill<<<(E + 255) / 256, 256, 0, stream>>>(src, dst, cur, csr_src, E);

    // layer 1
    k_xW1<<<(N * 64) / 256, 256, 0, stream>>>(x, W1, A, N);
    k_agg<<<(N * 16 + 255) / 256, 256, 0, stream>>>(A, csr_src, rowptr, dinv, B, N);

    // layer 2
    k_biasrelu_mm<<<(N * 64) / 256, 256, 0, stream>>>(B, b1, W2, A, N);
    k_agg<<<(N * 16 + 255) / 256, 256, 0, stream>>>(A, csr_src, rowptr, dinv, B, N);

    // pool + readout
    k_pool<<<(N * 64) / 256, 256, 0, stream>>>(B, b2, Wr, batch, gsum, gcnt, N);
    k_out<<<1, 64, 0, stream>>>(gsum, gcnt, br, out);
}

// Round 3
// 900.907 us; speedup vs baseline: 7.2942x; 1.8141x over previous
//
#include <hip/hip_runtime.h>

#define N_NODES  100000
#define N_EDGES  3200000
#define N_GRAPHS 64
#define SCAN_BLOCK 1024
#define POOL_BLOCKS 1024

// ---------------- degree histogram (in-degree by dst, no self-loop) ----------------
__global__ void k_degree(const int* __restrict__ dst, int* __restrict__ cnt, int E) {
    int i = blockIdx.x * blockDim.x + threadIdx.x;
    if (i < E) atomicAdd(&cnt[dst[i]], 1);
}

__global__ void k_dinv(const int* __restrict__ cnt, float* __restrict__ dinv, int N) {
    int i = blockIdx.x * blockDim.x + threadIdx.x;
    if (i < N) dinv[i] = 1.0f / sqrtf((float)(cnt[i] + 1));  // +1 self-loop
}

// ---------------- exclusive scan of cnt -> rowptr (3 kernels) ----------------
__global__ void k_scan1(const int* __restrict__ cnt, int* __restrict__ rowptr,
                        int* __restrict__ bsum, int N) {
    __shared__ int tmp[SCAN_BLOCK];
    int t = threadIdx.x, g = blockIdx.x * SCAN_BLOCK + t;
    int v = (g < N) ? cnt[g] : 0;
    tmp[t] = v;
    __syncthreads();
    for (int off = 1; off < SCAN_BLOCK; off <<= 1) {
        int add = (t >= off) ? tmp[t - off] : 0;
        __syncthreads();
        tmp[t] += add;
        __syncthreads();
    }
    if (g < N) rowptr[g] = tmp[t] - v;
    if (t == SCAN_BLOCK - 1) bsum[blockIdx.x] = tmp[t];
}

__global__ void k_scan2(int* __restrict__ bsum, int nb) {  // one block of 128
    __shared__ int tmp[128];
    int t = threadIdx.x;
    int v = (t < nb) ? bsum[t] : 0;
    tmp[t] = v;
    __syncthreads();
    for (int off = 1; off < 128; off <<= 1) {
        int add = (t >= off) ? tmp[t - off] : 0;
        __syncthreads();
        tmp[t] += add;
        __syncthreads();
    }
    if (t < nb) bsum[t] = tmp[t] - v;
}

__global__ void k_scan3(int* __restrict__ rowptr, const int* __restrict__ bsum,
                        int* __restrict__ cur, int N, int E) {
    int g = blockIdx.x * blockDim.x + threadIdx.x;
    if (g < N) {
        int r = rowptr[g] + bsum[g / SCAN_BLOCK];
        rowptr[g] = r;
        cur[g] = r;
    }
    if (g == 0) rowptr[N] = E;
}

// ---------------- CSR fill: bucket edges by dst ----------------
__global__ void k_fill(const int* __restrict__ src, const int* __restrict__ dst,
                       int* __restrict__ cur, int* __restrict__ csr_src, int E) {
    int i = blockIdx.x * blockDim.x + threadIdx.x;
    if (i >= E) return;
    int pos = atomicAdd(&cur[dst[i]], 1);
    csr_src[pos] = src[i];
}

// ---------------- H1 = x @ W1  (x: [N,3], W1: [3,64]) ----------------
__global__ void k_xW1(const float* __restrict__ x, const float* __restrict__ W1,
                      float* __restrict__ A, int N) {
    int tid = blockIdx.x * blockDim.x + threadIdx.x;
    int n = tid >> 6, f = tid & 63;
    if (n >= N) return;
    float x0 = x[n * 3 + 0], x1 = x[n * 3 + 1], x2 = x[n * 3 + 2];
    A[tid] = x0 * W1[f] + x1 * W1[64 + f] + x2 * W1[128 + f];
}

// ---------------- CSR gather-aggregate: 16 lanes per node, float4 regs ----------------
__global__ __launch_bounds__(256) void k_agg(
        const float* __restrict__ H, const int* __restrict__ csr_src,
        const int* __restrict__ rowptr, const float* __restrict__ dinv,
        float* __restrict__ out, int N) {
    int tid = blockIdx.x * blockDim.x + threadIdx.x;
    int n = tid >> 4, q = tid & 15;
    if (n >= N) return;
    int beg = rowptr[n], end = rowptr[n + 1];
    float dn = dinv[n];
    float4 acc = make_float4(0.f, 0.f, 0.f, 0.f);
    for (int i = beg; i < end; ++i) {
        int s = csr_src[i];
        float w = dinv[s] * dn;
        float4 h = ((const float4*)(H + (size_t)s * 64))[q];
        acc.x += w * h.x; acc.y += w * h.y; acc.z += w * h.z; acc.w += w * h.w;
    }
    float ws = dn * dn;  // self-loop
    float4 h = ((const float4*)(H + (size_t)n * 64))[q];
    acc.x += ws * h.x; acc.y += ws * h.y; acc.z += ws * h.z; acc.w += ws * h.w;
    ((float4*)(out + (size_t)n * 64))[q] = acc;
}

// ---------------- T = relu(AGG + b) @ W2 (wave per node, W2 in LDS) ----------------
__global__ __launch_bounds__(256) void k_biasrelu_mm(
        const float* __restrict__ AGG, const float* __restrict__ b,
        const float* __restrict__ W2, float* __restrict__ out, int N) {
    __shared__ float W2s[64 * 64];
    for (int i = threadIdx.x; i < 64 * 64; i += 256) W2s[i] = W2[i];
    __syncthreads();
    int tid = blockIdx.x * blockDim.x + threadIdx.x;
    int n = tid >> 6, f = tid & 63;
    if (n >= N) return;
    float r = fmaxf(AGG[(size_t)n * 64 + f] + b[f], 0.0f);
    float acc = 0.0f;
#pragma unroll 16
    for (int k = 0; k < 64; ++k) {
        float rk = __shfl(r, k);
        acc += rk * W2s[k * 64 + f];
    }
    out[(size_t)n * 64 + f] = acc;
}

// ---------------- hierarchical pool ----------------
// Each block owns a contiguous node chunk (batch sorted -> 1-2 graphs/block).
// Wave-per-node dot with Wr; lane0 -> LDS per-graph table; one global atomic
// per graph PRESENT in the block (~2/block vs 200k contended before).
__global__ __launch_bounds__(256) void k_pool(
        const float* __restrict__ AGG, const float* __restrict__ b2,
        const float* __restrict__ Wr, const int* __restrict__ batch,
        float* __restrict__ gsum, float* __restrict__ gcnt, int N) {
    __shared__ float lsum[N_GRAPHS];
    __shared__ float lcnt[N_GRAPHS];
    int t = threadIdx.x;
    if (t < N_GRAPHS) { lsum[t] = 0.f; lcnt[t] = 0.f; }
    __syncthreads();

    int lane = t & 63, wv = t >> 6;                    // 4 waves/block
    int chunk = (N + gridDim.x - 1) / gridDim.x;
    int n0 = blockIdx.x * chunk;
    int n1 = min(N, n0 + chunk);
    float wr = Wr[lane], bb = b2[lane];
    for (int n = n0 + wv; n < n1; n += 4) {
        float r = fmaxf(AGG[(size_t)n * 64 + lane] + bb, 0.0f) * wr;
        for (int off = 32; off > 0; off >>= 1) r += __shfl_down(r, off);
        if (lane == 0) {
            int g = batch[n];
            atomicAdd(&lsum[g], r);
            atomicAdd(&lcnt[g], 1.0f);
        }
    }
    __syncthreads();
    if (t < N_GRAPHS && lcnt[t] > 0.0f) {
        atomicAdd(&gsum[t], lsum[t]);
        atomicAdd(&gcnt[t], lcnt[t]);
    }
}

__global__ void k_out(const float* __restrict__ gsum, const float* __restrict__ gcnt,
                      const float* __restrict__ br, float* __restrict__ out) {
    int g = threadIdx.x;
    if (g < N_GRAPHS) out[g] = gsum[g] / fmaxf(gcnt[g], 1.0f) + br[0];
}

extern "C" void kernel_launch(void* const* d_in, const int* in_sizes, int n_in,
                              void* d_out, int out_size, void* d_ws, size_t ws_size,
                              hipStream_t stream) {
    const float* x     = (const float*)d_in[0];
    const int*   ei    = (const int*)d_in[1];   // [2, E]
    const int*   batch = (const int*)d_in[2];
    const float* W1    = (const float*)d_in[3];
    const float* b1    = (const float*)d_in[4];
    const float* W2    = (const float*)d_in[5];
    const float* b2    = (const float*)d_in[6];
    const float* Wr    = (const float*)d_in[7];
    const float* br    = (const float*)d_in[8];
    float* out = (float*)d_out;

    const int N = N_NODES, E = N_EDGES;
    const int NB = (N + SCAN_BLOCK - 1) / SCAN_BLOCK;
    const int* src = ei;
    const int* dst = ei + E;

    // workspace (~65 MB)
    char* w = (char*)d_ws;
    float* A       = (float*)w; w += (size_t)N * 64 * sizeof(float);
    float* B       = (float*)w; w += (size_t)N * 64 * sizeof(float);
    int*   csr_src = (int*)w;   w += (size_t)E * sizeof(int);
    float* dinv    = (float*)w; w += (size_t)N * sizeof(float);
    int*   cnt     = (int*)w;   w += (size_t)N * sizeof(int);
    int*   rowptr  = (int*)w;   w += (size_t)(N + 1) * sizeof(int);
    int*   cur     = (int*)w;   w += (size_t)N * sizeof(int);
    int*   bsum    = (int*)w;   w += 128 * sizeof(int);
    float* gsum    = (float*)w; w += N_GRAPHS * sizeof(float);
    float* gcnt    = (float*)w; w += N_GRAPHS * sizeof(float);

    hipMemsetAsync(cnt,  0, (size_t)N * sizeof(int), stream);
    hipMemsetAsync(gsum, 0, N_GRAPHS * sizeof(float), stream);
    hipMemsetAsync(gcnt, 0, N_GRAPHS * sizeof(float), stream);

    // CSR build
    k_degree<<<(E + 255) / 256, 256, 0, stream>>>(dst, cnt, E);
    k_dinv<<<(N + 255) / 256, 256, 0, stream>>>(cnt, dinv, N);
    k_scan1<<<NB, SCAN_BLOCK, 0, stream>>>(cnt, rowptr, bsum, N);
    k_scan2<<<1, 128, 0, stream>>>(bsum, NB);
    k_scan3<<<(N + 255) / 256, 256, 0, stream>>>(rowptr, bsum, cur, N, E);
    k_fill<<<(E + 255) / 256, 256, 0, stream>>>(src, dst, cur, csr_src, E);

    // layer 1
    k_xW1<<<(N * 64) / 256, 256, 0, stream>>>(x, W1, A, N);
    k_agg<<<(N * 16 + 255) / 256, 256, 0, stream>>>(A, csr_src, rowptr, dinv, B, N);

    // layer 2
    k_biasrelu_mm<<<(N * 64) / 256, 256, 0, stream>>>(B, b1, W2, A, N);
    k_agg<<<(N * 16 + 255) / 256, 256, 0, stream>>>(A, csr_src, rowptr, dinv, B, N);

    // pool + readout
    k_pool<<<POOL_BLOCKS, 256, 0, stream>>>(B, b2, Wr, batch, gsum, gcnt, N);
    k_out<<<1, 64, 0, stream>>>(gsum, gcnt, br, out);
}

// Round 4
// 772.904 us; speedup vs baseline: 8.5023x; 1.1656x over previous
//
#include <hip/hip_runtime.h>

#define N_NODES  100000
#define N_EDGES  3200000
#define N_GRAPHS 64
#define SCAN_BLOCK 1024
#define POOL_BLOCKS 1024

// ---------------- degree histogram (in-degree by dst, no self-loop) ----------------
__global__ void k_degree(const int* __restrict__ dst, int* __restrict__ cnt, int E) {
    int i = blockIdx.x * blockDim.x + threadIdx.x;
    if (i < E) atomicAdd(&cnt[dst[i]], 1);
}

__global__ void k_dinv(const int* __restrict__ cnt, float* __restrict__ dinv, int N) {
    int i = blockIdx.x * blockDim.x + threadIdx.x;
    if (i < N) dinv[i] = 1.0f / sqrtf((float)(cnt[i] + 1));  // +1 self-loop
}

// ---------------- exclusive scan of cnt -> rowptr ----------------
__global__ void k_scan1(const int* __restrict__ cnt, int* __restrict__ rowptr,
                        int* __restrict__ bsum, int N) {
    __shared__ int tmp[SCAN_BLOCK];
    int t = threadIdx.x, g = blockIdx.x * SCAN_BLOCK + t;
    int v = (g < N) ? cnt[g] : 0;
    tmp[t] = v;
    __syncthreads();
    for (int off = 1; off < SCAN_BLOCK; off <<= 1) {
        int add = (t >= off) ? tmp[t - off] : 0;
        __syncthreads();
        tmp[t] += add;
        __syncthreads();
    }
    if (g < N) rowptr[g] = tmp[t] - v;
    if (t == SCAN_BLOCK - 1) bsum[blockIdx.x] = tmp[t];
}

__global__ void k_scan2(int* __restrict__ bsum, int nb) {
    __shared__ int tmp[128];
    int t = threadIdx.x;
    int v = (t < nb) ? bsum[t] : 0;
    tmp[t] = v;
    __syncthreads();
    for (int off = 1; off < 128; off <<= 1) {
        int add = (t >= off) ? tmp[t - off] : 0;
        __syncthreads();
        tmp[t] += add;
        __syncthreads();
    }
    if (t < nb) bsum[t] = tmp[t] - v;
}

__global__ void k_scan3(int* __restrict__ rowptr, const int* __restrict__ bsum,
                        int* __restrict__ cur, int N, int E) {
    int g = blockIdx.x * blockDim.x + threadIdx.x;
    if (g < N) {
        int r = rowptr[g] + bsum[g / SCAN_BLOCK];
        rowptr[g] = r;
        cur[g] = r;
    }
    if (g == 0) rowptr[N] = E;
}

// ---------------- CSR fill: bucket edges by dst ----------------
__global__ void k_fill(const int* __restrict__ src, const int* __restrict__ dst,
                       int* __restrict__ cur, int* __restrict__ csr_src, int E) {
    int i = blockIdx.x * blockDim.x + threadIdx.x;
    if (i >= E) return;
    int pos = atomicAdd(&cur[dst[i]], 1);
    csr_src[pos] = src[i];
}

// ---------------- conv over RAW x (3 features): agg3[n] = conv(x)[n]  ----------------
// 4 lanes per node (q=0..3, q==3 is a dummy clamped to feature 2, not stored).
__global__ __launch_bounds__(256) void k_agg3(
        const float* __restrict__ x, const int* __restrict__ csr_src,
        const int* __restrict__ rowptr, const float* __restrict__ dinv,
        float* __restrict__ agg3, int N) {
    int tid = blockIdx.x * blockDim.x + threadIdx.x;
    int n = tid >> 2, q = tid & 3;
    if (n >= N) return;
    int qc = (q < 3) ? q : 2;  // clamp: avoid OOB x read for lane 3 of last node
    int beg = rowptr[n], end = rowptr[n + 1];
    float dn = dinv[n];
    float a0 = 0.f, a1 = 0.f;
    int i = beg;
    for (; i + 2 <= end; i += 2) {
        int s0 = csr_src[i], s1 = csr_src[i + 1];
        a0 += dinv[s0] * x[(size_t)s0 * 3 + qc];
        a1 += dinv[s1] * x[(size_t)s1 * 3 + qc];
    }
    if (i < end) {
        int s0 = csr_src[i];
        a0 += dinv[s0] * x[(size_t)s0 * 3 + qc];
    }
    float acc = (a0 + a1) * dn + dn * dn * x[(size_t)n * 3 + qc];
    if (q < 3) agg3[(size_t)n * 4 + q] = acc;
}

// ---------------- h1 = relu(agg3 @ W1 + b1)  (wave per node, lane = feature) --------
__global__ __launch_bounds__(256) void k_h1(
        const float* __restrict__ agg3, const float* __restrict__ W1,
        const float* __restrict__ b1, float* __restrict__ h1, int N) {
    int tid = blockIdx.x * blockDim.x + threadIdx.x;
    int n = tid >> 6, f = tid & 63;
    if (n >= N) return;
    float a0 = agg3[(size_t)n * 4 + 0];
    float a1 = agg3[(size_t)n * 4 + 1];
    float a2 = agg3[(size_t)n * 4 + 2];
    float v = a0 * W1[f] + a1 * W1[64 + f] + a2 * W1[128 + f] + b1[f];
    h1[(size_t)n * 64 + f] = fmaxf(v, 0.0f);
}

// ---------------- CSR gather-aggregate (64 feats): 16 lanes/node, 2-edge unroll -----
__global__ __launch_bounds__(256) void k_agg(
        const float* __restrict__ H, const int* __restrict__ csr_src,
        const int* __restrict__ rowptr, const float* __restrict__ dinv,
        float* __restrict__ out, int N) {
    int tid = blockIdx.x * blockDim.x + threadIdx.x;
    int n = tid >> 4, q = tid & 15;
    if (n >= N) return;
    int beg = rowptr[n], end = rowptr[n + 1];
    float dn = dinv[n];
    float4 acc0 = make_float4(0.f, 0.f, 0.f, 0.f);
    float4 acc1 = make_float4(0.f, 0.f, 0.f, 0.f);
    int i = beg;
    for (; i + 2 <= end; i += 2) {
        int s0 = csr_src[i], s1 = csr_src[i + 1];
        float w0 = dinv[s0], w1 = dinv[s1];
        float4 h0 = ((const float4*)(H + (size_t)s0 * 64))[q];
        float4 h1 = ((const float4*)(H + (size_t)s1 * 64))[q];
        acc0.x += w0 * h0.x; acc0.y += w0 * h0.y; acc0.z += w0 * h0.z; acc0.w += w0 * h0.w;
        acc1.x += w1 * h1.x; acc1.y += w1 * h1.y; acc1.z += w1 * h1.z; acc1.w += w1 * h1.w;
    }
    if (i < end) {
        int s0 = csr_src[i];
        float w0 = dinv[s0];
        float4 h0 = ((const float4*)(H + (size_t)s0 * 64))[q];
        acc0.x += w0 * h0.x; acc0.y += w0 * h0.y; acc0.z += w0 * h0.z; acc0.w += w0 * h0.w;
    }
    float ws = dn * dn;  // self-loop
    float4 h = ((const float4*)(H + (size_t)n * 64))[q];
    float4 r;
    r.x = (acc0.x + acc1.x) * dn + ws * h.x;
    r.y = (acc0.y + acc1.y) * dn + ws * h.y;
    r.z = (acc0.z + acc1.z) * dn + ws * h.z;
    r.w = (acc0.w + acc1.w) * dn + ws * h.w;
    ((float4*)(out + (size_t)n * 64))[q] = r;
}

// ---------------- fused: relu(agg2 @ W2 + b2) . Wr -> hierarchical pool -------------
__global__ __launch_bounds__(256) void k_mmpool(
        const float* __restrict__ agg2, const float* __restrict__ W2,
        const float* __restrict__ b2, const float* __restrict__ Wr,
        const int* __restrict__ batch, float* __restrict__ gsum,
        float* __restrict__ gcnt, int N) {
    __shared__ float W2s[64 * 64];
    __shared__ float lsum[N_GRAPHS];
    __shared__ float lcnt[N_GRAPHS];
    int t = threadIdx.x;
    for (int i = t; i < 64 * 64; i += 256) W2s[i] = W2[i];
    if (t < N_GRAPHS) { lsum[t] = 0.f; lcnt[t] = 0.f; }
    __syncthreads();

    int lane = t & 63, wv = t >> 6;  // 4 waves/block
    int chunk = (N + gridDim.x - 1) / gridDim.x;
    int n0 = blockIdx.x * chunk;
    int n1 = min(N, n0 + chunk);
    float wr = Wr[lane], bb = b2[lane];
    for (int n = n0 + wv; n < n1; n += 4) {
        float a = agg2[(size_t)n * 64 + lane];
        float acc = 0.0f;
#pragma unroll 16
        for (int k = 0; k < 64; ++k) {
            float ak = __shfl(a, k);
            acc += ak * W2s[k * 64 + lane];
        }
        float r = fmaxf(acc + bb, 0.0f) * wr;
        for (int off = 32; off > 0; off >>= 1) r += __shfl_down(r, off);
        if (lane == 0) {
            int g = batch[n];
            atomicAdd(&lsum[g], r);
            atomicAdd(&lcnt[g], 1.0f);
        }
    }
    __syncthreads();
    if (t < N_GRAPHS && lcnt[t] > 0.0f) {
        atomicAdd(&gsum[t], lsum[t]);
        atomicAdd(&gcnt[t], lcnt[t]);
    }
}

__global__ void k_out(const float* __restrict__ gsum, const float* __restrict__ gcnt,
                      const float* __restrict__ br, float* __restrict__ out) {
    int g = threadIdx.x;
    if (g < N_GRAPHS) out[g] = gsum[g] / fmaxf(gcnt[g], 1.0f) + br[0];
}

extern "C" void kernel_launch(void* const* d_in, const int* in_sizes, int n_in,
                              void* d_out, int out_size, void* d_ws, size_t ws_size,
                              hipStream_t stream) {
    const float* x     = (const float*)d_in[0];
    const int*   ei    = (const int*)d_in[1];   // [2, E]
    const int*   batch = (const int*)d_in[2];
    const float* W1    = (const float*)d_in[3];
    const float* b1    = (const float*)d_in[4];
    const float* W2    = (const float*)d_in[5];
    const float* b2    = (const float*)d_in[6];
    const float* Wr    = (const float*)d_in[7];
    const float* br    = (const float*)d_in[8];
    float* out = (float*)d_out;

    const int N = N_NODES, E = N_EDGES;
    const int NB = (N + SCAN_BLOCK - 1) / SCAN_BLOCK;
    const int* src = ei;
    const int* dst = ei + E;

    // workspace (~66 MB): A doubles as agg3 (first 4N floats) then agg2 (64N)
    char* w = (char*)d_ws;
    float* A       = (float*)w; w += (size_t)N * 64 * sizeof(float);  // agg3 / agg2
    float* B       = (float*)w; w += (size_t)N * 64 * sizeof(float);  // h1
    int*   csr_src = (int*)w;   w += (size_t)E * sizeof(int);
    float* dinv    = (float*)w; w += (size_t)N * sizeof(float);
    int*   cnt     = (int*)w;   w += (size_t)N * sizeof(int);
    int*   rowptr  = (int*)w;   w += (size_t)(N + 1) * sizeof(int);
    int*   cur     = (int*)w;   w += (size_t)N * sizeof(int);
    int*   bsum    = (int*)w;   w += 128 * sizeof(int);
    float* gsum    = (float*)w; w += N_GRAPHS * sizeof(float);
    float* gcnt    = (float*)w; w += N_GRAPHS * sizeof(float);

    hipMemsetAsync(cnt,  0, (size_t)N * sizeof(int), stream);
    hipMemsetAsync(gsum, 0, N_GRAPHS * sizeof(float), stream);
    hipMemsetAsync(gcnt, 0, N_GRAPHS * sizeof(float), stream);

    // CSR build
    k_degree<<<(E + 255) / 256, 256, 0, stream>>>(dst, cnt, E);
    k_dinv<<<(N + 255) / 256, 256, 0, stream>>>(cnt, dinv, N);
    k_scan1<<<NB, SCAN_BLOCK, 0, stream>>>(cnt, rowptr, bsum, N);
    k_scan2<<<1, 128, 0, stream>>>(bsum, NB);
    k_scan3<<<(N + 255) / 256, 256, 0, stream>>>(rowptr, bsum, cur, N, E);
    k_fill<<<(E + 255) / 256, 256, 0, stream>>>(src, dst, cur, csr_src, E);

    // layer 1: conv(x) (3-wide) then @W1+b1+relu
    k_agg3<<<(N * 4 + 255) / 256, 256, 0, stream>>>(x, csr_src, rowptr, dinv, A, N);
    k_h1<<<(N * 64) / 256, 256, 0, stream>>>(A, W1, b1, B, N);

    // layer 2: conv(h1) (64-wide), then fused @W2+b2+relu+.Wr+pool
    k_agg<<<(N * 16 + 255) / 256, 256, 0, stream>>>(B, csr_src, rowptr, dinv, A, N);
    k_mmpool<<<POOL_BLOCKS, 256, 0, stream>>>(A, W2, b2, Wr, batch, gsum, gcnt, N);

    k_out<<<1, 64, 0, stream>>>(gsum, gcnt, br, out);
}

// Round 5
// 557.870 us; speedup vs baseline: 11.7795x; 1.3855x over previous
//
#include <hip/hip_runtime.h>

#define N_NODES  100000
#define N_EDGES  3200000
#define N_GRAPHS 64
#define SCAN_BLOCK 1024
#define POOL_BLOCKS 1024
#define NBUCK 391          // ceil(100000 / 256)
#define TILE  4096         // edges per k_split block
#define CSR_CAP 9216       // max edges per bucket (mean 8192, sigma~90)

// ---------------- degree histogram (in-degree by dst, no self-loop) ----------------
__global__ void k_degree(const int* __restrict__ dst, int* __restrict__ cnt, int E) {
    int i = blockIdx.x * blockDim.x + threadIdx.x;
    if (i < E) atomicAdd(&cnt[dst[i]], 1);
}

__global__ void k_dinv(const int* __restrict__ cnt, float* __restrict__ dinv, int N) {
    int i = blockIdx.x * blockDim.x + threadIdx.x;
    if (i < N) dinv[i] = 1.0f / sqrtf((float)(cnt[i] + 1));  // +1 self-loop
}

// ---------------- exclusive scan of cnt -> rowptr ----------------
__global__ void k_scan1(const int* __restrict__ cnt, int* __restrict__ rowptr,
                        int* __restrict__ bsum, int N) {
    __shared__ int tmp[SCAN_BLOCK];
    int t = threadIdx.x, g = blockIdx.x * SCAN_BLOCK + t;
    int v = (g < N) ? cnt[g] : 0;
    tmp[t] = v;
    __syncthreads();
    for (int off = 1; off < SCAN_BLOCK; off <<= 1) {
        int add = (t >= off) ? tmp[t - off] : 0;
        __syncthreads();
        tmp[t] += add;
        __syncthreads();
    }
    if (g < N) rowptr[g] = tmp[t] - v;
    if (t == SCAN_BLOCK - 1) bsum[blockIdx.x] = tmp[t];
}

__global__ void k_scan2(int* __restrict__ bsum, int nb) {
    __shared__ int tmp[128];
    int t = threadIdx.x;
    int v = (t < nb) ? bsum[t] : 0;
    tmp[t] = v;
    __syncthreads();
    for (int off = 1; off < 128; off <<= 1) {
        int add = (t >= off) ? tmp[t - off] : 0;
        __syncthreads();
        tmp[t] += add;
        __syncthreads();
    }
    if (t < nb) bsum[t] = tmp[t] - v;
}

__global__ void k_scan3(int* __restrict__ rowptr, const int* __restrict__ bsum, int N, int E) {
    int g = blockIdx.x * blockDim.x + threadIdx.x;
    if (g < N) rowptr[g] = rowptr[g] + bsum[g / SCAN_BLOCK];
    if (g == 0) rowptr[N] = E;
}

// gcur[b] = rowptr[256*b]  (bucket region start == CSR region start)
__global__ void k_binit(const int* __restrict__ rowptr, int* __restrict__ gcur) {
    int b = blockIdx.x * blockDim.x + threadIdx.x;
    if (b < NBUCK) gcur[b] = rowptr[b << 8];
}

// ---------------- P1: multisplit edges into 391 dst-buckets (coalesced-ish) --------
__global__ __launch_bounds__(256) void k_split(
        const int* __restrict__ src, const int* __restrict__ dst,
        int* __restrict__ gcur, unsigned long long* __restrict__ ebuf, int E) {
    __shared__ int hist[512];
    __shared__ int scn[512];     // inclusive scan of hist
    __shared__ int base[NBUCK];  // global base per bucket (this block's range)
    __shared__ int curs[NBUCK];
    __shared__ unsigned long long stg[TILE];  // 32 KB staging
    int t = threadIdx.x;
    for (int i = t; i < 512; i += 256) hist[i] = 0;
    __syncthreads();

    int e0 = blockIdx.x * TILE;
    // pass 1: histogram
    for (int k = 0; k < TILE / 256; ++k) {
        int i = e0 + t + k * 256;
        if (i < E) atomicAdd(&hist[dst[i] >> 8], 1);
    }
    __syncthreads();
    // inclusive Hillis-Steele scan over 512 slots, 2 slots/thread
    scn[t] = hist[t]; scn[t + 256] = hist[t + 256];
    __syncthreads();
    for (int off = 1; off < 512; off <<= 1) {
        int v0 = (t >= off) ? scn[t - off] : 0;
        int v1 = (t + 256 >= off) ? scn[t + 256 - off] : 0;
        __syncthreads();
        scn[t] += v0; scn[t + 256] += v1;
        __syncthreads();
    }
    // reserve global ranges, zero cursors
    for (int b = t; b < NBUCK; b += 256) {
        int h = hist[b];
        if (h > 0) base[b] = atomicAdd(&gcur[b], h);
        curs[b] = 0;
    }
    __syncthreads();
    // pass 2: rank + stage
    for (int k = 0; k < TILE / 256; ++k) {
        int i = e0 + t + k * 256;
        if (i < E) {
            int s = src[i], d = dst[i];
            int b = d >> 8;
            int r = atomicAdd(&curs[b], 1);
            int loff = scn[b] - hist[b];  // exclusive
            stg[loff + r] = ((unsigned long long)(unsigned)d << 32) | (unsigned)s;
        }
    }
    __syncthreads();
    // coalesced flush: staging slot j belongs to bucket of its dst
    int nvalid = min(TILE, E - e0);
    for (int j = t; j < nvalid; j += 256) {
        unsigned long long p = stg[j];
        int d = (int)(p >> 32);
        int b = d >> 8;
        int loff = scn[b] - hist[b];
        ebuf[(size_t)base[b] + (j - loff)] = p;
    }
}

// ---------------- P2: bucket -> per-node CSR (coalesced writes) ----------------
__global__ __launch_bounds__(256) void k_csr(
        const unsigned long long* __restrict__ ebuf, const int* __restrict__ rowptr,
        int* __restrict__ csr_src, int N) {
    __shared__ int nbase[257];
    __shared__ int ncur[256];
    __shared__ int stg[CSR_CAP];  // 36 KB
    int b = blockIdx.x, t = threadIdx.x;
    int node0 = b << 8;
    int nodes = min(256, N - node0);
    int r0 = rowptr[node0];
    int r1 = rowptr[node0 + nodes];
    int cnt = r1 - r0;
    if (t <= nodes) nbase[t] = rowptr[node0 + t] - r0;
    if (t < 256) ncur[t] = 0;
    __syncthreads();
    if (cnt <= CSR_CAP) {
        for (int j = t; j < cnt; j += 256) {
            unsigned long long p = ebuf[(size_t)r0 + j];
            int s = (int)(p & 0xffffffffu);
            int ln = ((int)(p >> 32)) & 255;
            int r = atomicAdd(&ncur[ln], 1);
            stg[nbase[ln] + r] = s;
        }
        __syncthreads();
        for (int j = t; j < cnt; j += 256) csr_src[(size_t)r0 + j] = stg[j];
    } else {  // overflow fallback: direct (uncoalesced) stores
        for (int j = t; j < cnt; j += 256) {
            unsigned long long p = ebuf[(size_t)r0 + j];
            int s = (int)(p & 0xffffffffu);
            int ln = ((int)(p >> 32)) & 255;
            int r = atomicAdd(&ncur[ln], 1);
            csr_src[(size_t)(r0 + nbase[ln] + r)] = s;
        }
    }
}

// ---------------- conv over RAW x (3 features) ----------------
__global__ __launch_bounds__(256) void k_agg3(
        const float* __restrict__ x, const int* __restrict__ csr_src,
        const int* __restrict__ rowptr, const float* __restrict__ dinv,
        float* __restrict__ agg3, int N) {
    int tid = blockIdx.x * blockDim.x + threadIdx.x;
    int n = tid >> 2, q = tid & 3;
    if (n >= N) return;
    int qc = (q < 3) ? q : 2;
    int beg = rowptr[n], end = rowptr[n + 1];
    float dn = dinv[n];
    float a0 = 0.f, a1 = 0.f;
    int i = beg;
    for (; i + 2 <= end; i += 2) {
        int s0 = csr_src[i], s1 = csr_src[i + 1];
        a0 += dinv[s0] * x[(size_t)s0 * 3 + qc];
        a1 += dinv[s1] * x[(size_t)s1 * 3 + qc];
    }
    if (i < end) {
        int s0 = csr_src[i];
        a0 += dinv[s0] * x[(size_t)s0 * 3 + qc];
    }
    float acc = (a0 + a1) * dn + dn * dn * x[(size_t)n * 3 + qc];
    if (q < 3) agg3[(size_t)n * 4 + q] = acc;
}

// ---------------- h1 = relu(agg3 @ W1 + b1) ----------------
__global__ __launch_bounds__(256) void k_h1(
        const float* __restrict__ agg3, const float* __restrict__ W1,
        const float* __restrict__ b1, float* __restrict__ h1, int N) {
    int tid = blockIdx.x * blockDim.x + threadIdx.x;
    int n = tid >> 6, f = tid & 63;
    if (n >= N) return;
    float a0 = agg3[(size_t)n * 4 + 0];
    float a1 = agg3[(size_t)n * 4 + 1];
    float a2 = agg3[(size_t)n * 4 + 2];
    float v = a0 * W1[f] + a1 * W1[64 + f] + a2 * W1[128 + f] + b1[f];
    h1[(size_t)n * 64 + f] = fmaxf(v, 0.0f);
}

// ---------------- CSR gather-aggregate (64 feats) ----------------
__global__ __launch_bounds__(256) void k_agg(
        const float* __restrict__ H, const int* __restrict__ csr_src,
        const int* __restrict__ rowptr, const float* __restrict__ dinv,
        float* __restrict__ out, int N) {
    int tid = blockIdx.x * blockDim.x + threadIdx.x;
    int n = tid >> 4, q = tid & 15;
    if (n >= N) return;
    int beg = rowptr[n], end = rowptr[n + 1];
    float dn = dinv[n];
    float4 acc0 = make_float4(0.f, 0.f, 0.f, 0.f);
    float4 acc1 = make_float4(0.f, 0.f, 0.f, 0.f);
    int i = beg;
    for (; i + 2 <= end; i += 2) {
        int s0 = csr_src[i], s1 = csr_src[i + 1];
        float w0 = dinv[s0], w1 = dinv[s1];
        float4 h0 = ((const float4*)(H + (size_t)s0 * 64))[q];
        float4 h1 = ((const float4*)(H + (size_t)s1 * 64))[q];
        acc0.x += w0 * h0.x; acc0.y += w0 * h0.y; acc0.z += w0 * h0.z; acc0.w += w0 * h0.w;
        acc1.x += w1 * h1.x; acc1.y += w1 * h1.y; acc1.z += w1 * h1.z; acc1.w += w1 * h1.w;
    }
    if (i < end) {
        int s0 = csr_src[i];
        float w0 = dinv[s0];
        float4 h0 = ((const float4*)(H + (size_t)s0 * 64))[q];
        acc0.x += w0 * h0.x; acc0.y += w0 * h0.y; acc0.z += w0 * h0.z; acc0.w += w0 * h0.w;
    }
    float ws = dn * dn;
    float4 h = ((const float4*)(H + (size_t)n * 64))[q];
    float4 r;
    r.x = (acc0.x + acc1.x) * dn + ws * h.x;
    r.y = (acc0.y + acc1.y) * dn + ws * h.y;
    r.z = (acc0.z + acc1.z) * dn + ws * h.z;
    r.w = (acc0.w + acc1.w) * dn + ws * h.w;
    ((float4*)(out + (size_t)n * 64))[q] = r;
}

// ---------------- fused: relu(agg2 @ W2 + b2) . Wr -> hierarchical pool ------------
__global__ __launch_bounds__(256) void k_mmpool(
        const float* __restrict__ agg2, const float* __restrict__ W2,
        const float* __restrict__ b2, const float* __restrict__ Wr,
        const int* __restrict__ batch, float* __restrict__ gsum,
        float* __restrict__ gcnt, int N) {
    __shared__ float W2s[64 * 64];
    __shared__ float lsum[N_GRAPHS];
    __shared__ float lcnt[N_GRAPHS];
    int t = threadIdx.x;
    for (int i = t; i < 64 * 64; i += 256) W2s[i] = W2[i];
    if (t < N_GRAPHS) { lsum[t] = 0.f; lcnt[t] = 0.f; }
    __syncthreads();

    int lane = t & 63, wv = t >> 6;
    int chunk = (N + gridDim.x - 1) / gridDim.x;
    int n0 = blockIdx.x * chunk;
    int n1 = min(N, n0 + chunk);
    float wr = Wr[lane], bb = b2[lane];
    for (int n = n0 + wv; n < n1; n += 4) {
        float a = agg2[(size_t)n * 64 + lane];
        float acc = 0.0f;
#pragma unroll 16
        for (int k = 0; k < 64; ++k) {
            float ak = __shfl(a, k);
            acc += ak * W2s[k * 64 + lane];
        }
        float r = fmaxf(acc + bb, 0.0f) * wr;
        for (int off = 32; off > 0; off >>= 1) r += __shfl_down(r, off);
        if (lane == 0) {
            int g = batch[n];
            atomicAdd(&lsum[g], r);
            atomicAdd(&lcnt[g], 1.0f);
        }
    }
    __syncthreads();
    if (t < N_GRAPHS && lcnt[t] > 0.0f) {
        atomicAdd(&gsum[t], lsum[t]);
        atomicAdd(&gcnt[t], lcnt[t]);
    }
}

__global__ void k_out(const float* __restrict__ gsum, const float* __restrict__ gcnt,
                      const float* __restrict__ br, float* __restrict__ out) {
    int g = threadIdx.x;
    if (g < N_GRAPHS) out[g] = gsum[g] / fmaxf(gcnt[g], 1.0f) + br[0];
}

extern "C" void kernel_launch(void* const* d_in, const int* in_sizes, int n_in,
                              void* d_out, int out_size, void* d_ws, size_t ws_size,
                              hipStream_t stream) {
    const float* x     = (const float*)d_in[0];
    const int*   ei    = (const int*)d_in[1];   // [2, E]
    const int*   batch = (const int*)d_in[2];
    const float* W1    = (const float*)d_in[3];
    const float* b1    = (const float*)d_in[4];
    const float* W2    = (const float*)d_in[5];
    const float* b2    = (const float*)d_in[6];
    const float* Wr    = (const float*)d_in[7];
    const float* br    = (const float*)d_in[8];
    float* out = (float*)d_out;

    const int N = N_NODES, E = N_EDGES;
    const int NB = (N + SCAN_BLOCK - 1) / SCAN_BLOCK;
    const int* src = ei;
    const int* dst = ei + E;

    // workspace: ebuf aliases A (both 25.6 MB; A written only after CSR build)
    char* w = (char*)d_ws;
    float* A       = (float*)w; w += (size_t)N * 64 * sizeof(float);  // agg3/agg2/ebuf
    float* B       = (float*)w; w += (size_t)N * 64 * sizeof(float);  // h1
    int*   csr_src = (int*)w;   w += (size_t)E * sizeof(int);
    float* dinv    = (float*)w; w += (size_t)N * sizeof(float);
    int*   cnt     = (int*)w;   w += (size_t)N * sizeof(int);
    int*   rowptr  = (int*)w;   w += (size_t)(N + 1) * sizeof(int);
    int*   gcur    = (int*)w;   w += (size_t)NBUCK * sizeof(int);
    int*   bsum    = (int*)w;   w += 128 * sizeof(int);
    float* gsum    = (float*)w; w += N_GRAPHS * sizeof(float);
    float* gcnt    = (float*)w; w += N_GRAPHS * sizeof(float);
    unsigned long long* ebuf = (unsigned long long*)A;

    hipMemsetAsync(cnt,  0, (size_t)N * sizeof(int), stream);
    hipMemsetAsync(gsum, 0, N_GRAPHS * sizeof(float), stream);
    hipMemsetAsync(gcnt, 0, N_GRAPHS * sizeof(float), stream);

    // CSR build
    k_degree<<<(E + 255) / 256, 256, 0, stream>>>(dst, cnt, E);
    k_dinv<<<(N + 255) / 256, 256, 0, stream>>>(cnt, dinv, N);
    k_scan1<<<NB, SCAN_BLOCK, 0, stream>>>(cnt, rowptr, bsum, N);
    k_scan2<<<1, 128, 0, stream>>>(bsum, NB);
    k_scan3<<<(N + 255) / 256, 256, 0, stream>>>(rowptr, bsum, N, E);
    k_binit<<<(NBUCK + 255) / 256, 256, 0, stream>>>(rowptr, gcur);
    k_split<<<(E + TILE - 1) / TILE, 256, 0, stream>>>(src, dst, gcur, ebuf, E);
    k_csr<<<NBUCK, 256, 0, stream>>>(ebuf, rowptr, csr_src, N);

    // layer 1: conv(x) (3-wide) then @W1+b1+relu
    k_agg3<<<(N * 4 + 255) / 256, 256, 0, stream>>>(x, csr_src, rowptr, dinv, A, N);
    k_h1<<<(N * 64) / 256, 256, 0, stream>>>(A, W1, b1, B, N);

    // layer 2: conv(h1) (64-wide), then fused @W2+b2+relu+.Wr+pool
    k_agg<<<(N * 16 + 255) / 256, 256, 0, stream>>>(B, csr_src, rowptr, dinv, A, N);
    k_mmpool<<<POOL_BLOCKS, 256, 0, stream>>>(A, W2, b2, Wr, batch, gsum, gcnt, N);

    k_out<<<1, 64, 0, stream>>>(gsum, gcnt, br, out);
}

// Round 6
// 440.969 us; speedup vs baseline: 14.9022x; 1.2651x over previous
//
#include <hip/hip_runtime.h>

#define N_NODES  100000
#define N_EDGES  3200000
#define N_GRAPHS 64
#define POOL_BLOCKS 1024
#define NBUCK 391          // ceil(100000 / 256)
#define TILE  4096         // edges per k_split block
#define CSR_CAP 9216       // fixed bucket capacity (mean 8192, sigma~90 -> 11 sigma)

// ---------------- P1: multisplit edges into 391 fixed-capacity dst-buckets ---------
__global__ __launch_bounds__(256) void k_split(
        const int* __restrict__ src, const int* __restrict__ dst,
        int* __restrict__ gcur, unsigned long long* __restrict__ ebuf, int E) {
    __shared__ int hist[512];
    __shared__ int scn[512];     // inclusive scan of hist
    __shared__ int base[NBUCK];  // offset inside bucket's fixed region
    __shared__ int curs[NBUCK];
    __shared__ unsigned long long stg[TILE];  // 32 KB staging
    int t = threadIdx.x;
    for (int i = t; i < 512; i += 256) hist[i] = 0;
    __syncthreads();

    int e0 = blockIdx.x * TILE;
    // pass 1: histogram over buckets (dst>>8)
    for (int k = 0; k < TILE / 256; ++k) {
        int i = e0 + t + k * 256;
        if (i < E) atomicAdd(&hist[dst[i] >> 8], 1);
    }
    __syncthreads();
    // inclusive Hillis-Steele scan over 512 slots, 2 slots/thread
    scn[t] = hist[t]; scn[t + 256] = hist[t + 256];
    __syncthreads();
    for (int off = 1; off < 512; off <<= 1) {
        int v0 = (t >= off) ? scn[t - off] : 0;
        int v1 = (t + 256 >= off) ? scn[t + 256 - off] : 0;
        __syncthreads();
        scn[t] += v0; scn[t + 256] += v1;
        __syncthreads();
    }
    // reserve range inside each bucket's fixed region
    for (int b = t; b < NBUCK; b += 256) {
        int h = hist[b];
        if (h > 0) base[b] = atomicAdd(&gcur[b], h);
        curs[b] = 0;
    }
    __syncthreads();
    // pass 2: rank + stage (bucket-contiguous in LDS)
    for (int k = 0; k < TILE / 256; ++k) {
        int i = e0 + t + k * 256;
        if (i < E) {
            int s = src[i], d = dst[i];
            int b = d >> 8;
            int r = atomicAdd(&curs[b], 1);
            int loff = scn[b] - hist[b];  // exclusive
            stg[loff + r] = ((unsigned long long)(unsigned)d << 32) | (unsigned)s;
        }
    }
    __syncthreads();
    // coalesced flush into fixed bucket regions
    int nvalid = min(TILE, E - e0);
    for (int j = t; j < nvalid; j += 256) {
        unsigned long long p = stg[j];
        int d = (int)(p >> 32);
        int b = d >> 8;
        int loff = scn[b] - hist[b];
        int pos = base[b] + (j - loff);
        if (pos < CSR_CAP) ebuf[(size_t)b * CSR_CAP + pos] = p;  // clamp guard
    }
}

// ---------------- bucket totals -> global CSR bases (single block) ----------------
__global__ void k_bscan(const int* __restrict__ gcur, int* __restrict__ bbase,
                        int* __restrict__ rowptr) {
    __shared__ int tmp[512];
    int t = threadIdx.x;
    int v = (t < NBUCK) ? gcur[t] : 0;
    tmp[t] = v;
    __syncthreads();
    for (int off = 1; off < 512; off <<= 1) {
        int add = (t >= off) ? tmp[t - off] : 0;
        __syncthreads();
        tmp[t] += add;
        __syncthreads();
    }
    if (t < NBUCK) bbase[t] = tmp[t] - v;  // exclusive
    if (t == 0) rowptr[N_NODES] = N_EDGES;
}

// ---------------- P2: bucket -> per-node degree + rowptr + dinv + CSR --------------
__global__ __launch_bounds__(256) void k_csr(
        const unsigned long long* __restrict__ ebuf, const int* __restrict__ gcur,
        const int* __restrict__ bbase, int* __restrict__ rowptr,
        float* __restrict__ dinv, int* __restrict__ csr_src, int N) {
    __shared__ int ncnt[256];
    __shared__ int nbase[256];
    __shared__ int ncur[256];
    __shared__ int stg[CSR_CAP];  // 36 KB
    int b = blockIdx.x, t = threadIdx.x;
    int node0 = b << 8;
    int nodes = min(256, N - node0);
    int cntE = min(gcur[b], CSR_CAP);
    int base = bbase[b];
    const unsigned long long* eb = ebuf + (size_t)b * CSR_CAP;
    ncnt[t] = 0; ncur[t] = 0;
    __syncthreads();
    // per-node in-degree (LDS atomics, <=256 counters)
    for (int j = t; j < cntE; j += 256) {
        int ln = ((int)(eb[j] >> 32)) & 255;
        atomicAdd(&ncnt[ln], 1);
    }
    __syncthreads();
    int v = ncnt[t];
    // exclusive scan of ncnt
    nbase[t] = v;
    __syncthreads();
    for (int off = 1; off < 256; off <<= 1) {
        int add = (t >= off) ? nbase[t - off] : 0;
        __syncthreads();
        nbase[t] += add;
        __syncthreads();
    }
    int excl = nbase[t] - v;
    __syncthreads();
    nbase[t] = excl;
    __syncthreads();
    if (t < nodes) {
        rowptr[node0 + t] = base + excl;
        dinv[node0 + t] = rsqrtf((float)(v + 1));  // +1 self-loop
    }
    // rank into LDS staging (node-contiguous)
    for (int j = t; j < cntE; j += 256) {
        unsigned long long p = eb[j];
        int s = (int)(p & 0xffffffffu);
        int ln = ((int)(p >> 32)) & 255;
        int r = atomicAdd(&ncur[ln], 1);
        stg[nbase[ln] + r] = s;
    }
    __syncthreads();
    // coalesced CSR flush
    for (int j = t; j < cntE; j += 256) csr_src[(size_t)base + j] = stg[j];
}

// ---------------- conv over RAW x (3 features) ----------------
__global__ __launch_bounds__(256) void k_agg3(
        const float* __restrict__ x, const int* __restrict__ csr_src,
        const int* __restrict__ rowptr, const float* __restrict__ dinv,
        float* __restrict__ agg3, int N) {
    int tid = blockIdx.x * blockDim.x + threadIdx.x;
    int n = tid >> 2, q = tid & 3;
    if (n >= N) return;
    int qc = (q < 3) ? q : 2;
    int beg = rowptr[n], end = rowptr[n + 1];
    float dn = dinv[n];
    float a0 = 0.f, a1 = 0.f;
    int i = beg;
    for (; i + 2 <= end; i += 2) {
        int s0 = csr_src[i], s1 = csr_src[i + 1];
        a0 += dinv[s0] * x[(size_t)s0 * 3 + qc];
        a1 += dinv[s1] * x[(size_t)s1 * 3 + qc];
    }
    if (i < end) {
        int s0 = csr_src[i];
        a0 += dinv[s0] * x[(size_t)s0 * 3 + qc];
    }
    float acc = (a0 + a1) * dn + dn * dn * x[(size_t)n * 3 + qc];
    if (q < 3) agg3[(size_t)n * 4 + q] = acc;
}

// ---------------- h1 = relu(agg3 @ W1 + b1) ----------------
__global__ __launch_bounds__(256) void k_h1(
        const float* __restrict__ agg3, const float* __restrict__ W1,
        const float* __restrict__ b1, float* __restrict__ h1, int N) {
    int tid = blockIdx.x * blockDim.x + threadIdx.x;
    int n = tid >> 6, f = tid & 63;
    if (n >= N) return;
    float a0 = agg3[(size_t)n * 4 + 0];
    float a1 = agg3[(size_t)n * 4 + 1];
    float a2 = agg3[(size_t)n * 4 + 2];
    float v = a0 * W1[f] + a1 * W1[64 + f] + a2 * W1[128 + f] + b1[f];
    h1[(size_t)n * 64 + f] = fmaxf(v, 0.0f);
}

// ---------------- CSR gather-aggregate (64 feats) ----------------
__global__ __launch_bounds__(256) void k_agg(
        const float* __restrict__ H, const int* __restrict__ csr_src,
        const int* __restrict__ rowptr, const float* __restrict__ dinv,
        float* __restrict__ out, int N) {
    int tid = blockIdx.x * blockDim.x + threadIdx.x;
    int n = tid >> 4, q = tid & 15;
    if (n >= N) return;
    int beg = rowptr[n], end = rowptr[n + 1];
    float dn = dinv[n];
    float4 acc0 = make_float4(0.f, 0.f, 0.f, 0.f);
    float4 acc1 = make_float4(0.f, 0.f, 0.f, 0.f);
    int i = beg;
    for (; i + 2 <= end; i += 2) {
        int s0 = csr_src[i], s1 = csr_src[i + 1];
        float w0 = dinv[s0], w1 = dinv[s1];
        float4 h0 = ((const float4*)(H + (size_t)s0 * 64))[q];
        float4 h1 = ((const float4*)(H + (size_t)s1 * 64))[q];
        acc0.x += w0 * h0.x; acc0.y += w0 * h0.y; acc0.z += w0 * h0.z; acc0.w += w0 * h0.w;
        acc1.x += w1 * h1.x; acc1.y += w1 * h1.y; acc1.z += w1 * h1.z; acc1.w += w1 * h1.w;
    }
    if (i < end) {
        int s0 = csr_src[i];
        float w0 = dinv[s0];
        float4 h0 = ((const float4*)(H + (size_t)s0 * 64))[q];
        acc0.x += w0 * h0.x; acc0.y += w0 * h0.y; acc0.z += w0 * h0.z; acc0.w += w0 * h0.w;
    }
    float ws = dn * dn;
    float4 h = ((const float4*)(H + (size_t)n * 64))[q];
    float4 r;
    r.x = (acc0.x + acc1.x) * dn + ws * h.x;
    r.y = (acc0.y + acc1.y) * dn + ws * h.y;
    r.z = (acc0.z + acc1.z) * dn + ws * h.z;
    r.w = (acc0.w + acc1.w) * dn + ws * h.w;
    ((float4*)(out + (size_t)n * 64))[q] = r;
}

// ---------------- fused: relu(agg2 @ W2 + b2) . Wr -> hierarchical pool ------------
__global__ __launch_bounds__(256) void k_mmpool(
        const float* __restrict__ agg2, const float* __restrict__ W2,
        const float* __restrict__ b2, const float* __restrict__ Wr,
        const int* __restrict__ batch, float* __restrict__ gsum,
        float* __restrict__ gcnt, int N) {
    __shared__ float W2s[64 * 64];
    __shared__ float lsum[N_GRAPHS];
    __shared__ float lcnt[N_GRAPHS];
    int t = threadIdx.x;
    for (int i = t; i < 64 * 64; i += 256) W2s[i] = W2[i];
    if (t < N_GRAPHS) { lsum[t] = 0.f; lcnt[t] = 0.f; }
    __syncthreads();

    int lane = t & 63, wv = t >> 6;
    int chunk = (N + gridDim.x - 1) / gridDim.x;
    int n0 = blockIdx.x * chunk;
    int n1 = min(N, n0 + chunk);
    float wr = Wr[lane], bb = b2[lane];
    for (int n = n0 + wv; n < n1; n += 4) {
        float a = agg2[(size_t)n * 64 + lane];
        float acc = 0.0f;
#pragma unroll 16
        for (int k = 0; k < 64; ++k) {
            float ak = __shfl(a, k);
            acc += ak * W2s[k * 64 + lane];
        }
        float r = fmaxf(acc + bb, 0.0f) * wr;
        for (int off = 32; off > 0; off >>= 1) r += __shfl_down(r, off);
        if (lane == 0) {
            int g = batch[n];
            atomicAdd(&lsum[g], r);
            atomicAdd(&lcnt[g], 1.0f);
        }
    }
    __syncthreads();
    if (t < N_GRAPHS && lcnt[t] > 0.0f) {
        atomicAdd(&gsum[t], lsum[t]);
        atomicAdd(&gcnt[t], lcnt[t]);
    }
}

__global__ void k_out(const float* __restrict__ gsum, const float* __restrict__ gcnt,
                      const float* __restrict__ br, float* __restrict__ out) {
    int g = threadIdx.x;
    if (g < N_GRAPHS) out[g] = gsum[g] / fmaxf(gcnt[g], 1.0f) + br[0];
}

extern "C" void kernel_launch(void* const* d_in, const int* in_sizes, int n_in,
                              void* d_out, int out_size, void* d_ws, size_t ws_size,
                              hipStream_t stream) {
    const float* x     = (const float*)d_in[0];
    const int*   ei    = (const int*)d_in[1];   // [2, E]
    const int*   batch = (const int*)d_in[2];
    const float* W1    = (const float*)d_in[3];
    const float* b1    = (const float*)d_in[4];
    const float* W2    = (const float*)d_in[5];
    const float* b2    = (const float*)d_in[6];
    const float* Wr    = (const float*)d_in[7];
    const float* br    = (const float*)d_in[8];
    float* out = (float*)d_out;

    const int N = N_NODES, E = N_EDGES;
    const int* src = ei;
    const int* dst = ei + E;

    // workspace: ebuf (28.8 MB) aliases A+front-of-B (both dead until CSR built)
    char* w = (char*)d_ws;
    float* A       = (float*)w; w += (size_t)N * 64 * sizeof(float);  // agg3/agg2
    float* B       = (float*)w; w += (size_t)N * 64 * sizeof(float);  // h1
    int*   csr_src = (int*)w;   w += (size_t)E * sizeof(int);
    float* dinv    = (float*)w; w += (size_t)N * sizeof(float);
    int*   rowptr  = (int*)w;   w += (size_t)(N + 1) * sizeof(int);
    int*   gcur    = (int*)w;   w += (size_t)NBUCK * sizeof(int);
    int*   bbase   = (int*)w;   w += (size_t)NBUCK * sizeof(int);
    float* gsum    = (float*)w; w += N_GRAPHS * sizeof(float);
    float* gcnt    = (float*)w; w += N_GRAPHS * sizeof(float);
    unsigned long long* ebuf = (unsigned long long*)A;  // spans into B; dead before use

    hipMemsetAsync(gcur, 0, (size_t)NBUCK * sizeof(int), stream);
    hipMemsetAsync(gsum, 0, N_GRAPHS * sizeof(float), stream);
    hipMemsetAsync(gcnt, 0, N_GRAPHS * sizeof(float), stream);

    // CSR build: split -> bucket-base scan -> per-bucket degree/rowptr/dinv/CSR
    k_split<<<(E + TILE - 1) / TILE, 256, 0, stream>>>(src, dst, gcur, ebuf, E);
    k_bscan<<<1, 512, 0, stream>>>(gcur, bbase, rowptr);
    k_csr<<<NBUCK, 256, 0, stream>>>(ebuf, gcur, bbase, rowptr, dinv, csr_src, N);

    // layer 1: conv(x) (3-wide) then @W1+b1+relu
    k_agg3<<<(N * 4 + 255) / 256, 256, 0, stream>>>(x, csr_src, rowptr, dinv, A, N);
    k_h1<<<(N * 64) / 256, 256, 0, stream>>>(A, W1, b1, B, N);

    // layer 2: conv(h1) (64-wide), then fused @W2+b2+relu+.Wr+pool
    k_agg<<<(N * 16 + 255) / 256, 256, 0, stream>>>(B, csr_src, rowptr, dinv, A, N);
    k_mmpool<<<POOL_BLOCKS, 256, 0, stream>>>(A, W2, b2, Wr, batch, gsum, gcnt, N);

    k_out<<<1, 64, 0, stream>>>(gsum, gcnt, br, out);
}

// Round 7
// 427.926 us; speedup vs baseline: 15.3564x; 1.0305x over previous
//
#include <hip/hip_runtime.h>

#define N_NODES  100000
#define N_EDGES  3200000
#define N_GRAPHS 64
#define POOL_BLOCKS 1024
#define NBUCK 391          // ceil(100000 / 256)
#define TILE  4096         // edges per k_split block
#define CSR_CAP 9216       // fixed bucket capacity (mean 8192, sigma~90 -> 11 sigma)

// ---------------- P1: multisplit edges into 391 fixed-capacity dst-buckets ---------
__global__ __launch_bounds__(256) void k_split(
        const int* __restrict__ src, const int* __restrict__ dst,
        int* __restrict__ gcur, unsigned long long* __restrict__ ebuf, int E) {
    __shared__ int hist[512];
    __shared__ int scn[512];
    __shared__ int base[NBUCK];
    __shared__ int curs[NBUCK];
    __shared__ unsigned long long stg[TILE];  // 32 KB staging
    int t = threadIdx.x;
    for (int i = t; i < 512; i += 256) hist[i] = 0;
    __syncthreads();

    int e0 = blockIdx.x * TILE;
    for (int k = 0; k < TILE / 256; ++k) {
        int i = e0 + t + k * 256;
        if (i < E) atomicAdd(&hist[dst[i] >> 8], 1);
    }
    __syncthreads();
    scn[t] = hist[t]; scn[t + 256] = hist[t + 256];
    __syncthreads();
    for (int off = 1; off < 512; off <<= 1) {
        int v0 = (t >= off) ? scn[t - off] : 0;
        int v1 = (t + 256 >= off) ? scn[t + 256 - off] : 0;
        __syncthreads();
        scn[t] += v0; scn[t + 256] += v1;
        __syncthreads();
    }
    for (int b = t; b < NBUCK; b += 256) {
        int h = hist[b];
        if (h > 0) base[b] = atomicAdd(&gcur[b], h);
        curs[b] = 0;
    }
    __syncthreads();
    for (int k = 0; k < TILE / 256; ++k) {
        int i = e0 + t + k * 256;
        if (i < E) {
            int s = src[i], d = dst[i];
            int b = d >> 8;
            int r = atomicAdd(&curs[b], 1);
            int loff = scn[b] - hist[b];
            stg[loff + r] = ((unsigned long long)(unsigned)d << 32) | (unsigned)s;
        }
    }
    __syncthreads();
    int nvalid = min(TILE, E - e0);
    for (int j = t; j < nvalid; j += 256) {
        unsigned long long p = stg[j];
        int d = (int)(p >> 32);
        int b = d >> 8;
        int loff = scn[b] - hist[b];
        int pos = base[b] + (j - loff);
        if (pos < CSR_CAP) ebuf[(size_t)b * CSR_CAP + pos] = p;
    }
}

// ---------------- bucket totals -> global CSR bases (single block) ----------------
__global__ void k_bscan(const int* __restrict__ gcur, int* __restrict__ bbase,
                        int* __restrict__ rowptr) {
    __shared__ int tmp[512];
    int t = threadIdx.x;
    int v = (t < NBUCK) ? gcur[t] : 0;
    tmp[t] = v;
    __syncthreads();
    for (int off = 1; off < 512; off <<= 1) {
        int add = (t >= off) ? tmp[t - off] : 0;
        __syncthreads();
        tmp[t] += add;
        __syncthreads();
    }
    if (t < NBUCK) bbase[t] = tmp[t] - v;
    if (t == 0) rowptr[N_NODES] = N_EDGES;
}

// ---------------- P2: bucket -> per-node degree + rowptr + dinv + CSR --------------
__global__ __launch_bounds__(256) void k_csr(
        const unsigned long long* __restrict__ ebuf, const int* __restrict__ gcur,
        const int* __restrict__ bbase, int* __restrict__ rowptr,
        float* __restrict__ dinv, int* __restrict__ csr_src, int N) {
    __shared__ int ncnt[256];
    __shared__ int nbase[256];
    __shared__ int ncur[256];
    __shared__ int stg[CSR_CAP];  // 36 KB
    int b = blockIdx.x, t = threadIdx.x;
    int node0 = b << 8;
    int nodes = min(256, N - node0);
    int cntE = min(gcur[b], CSR_CAP);
    int base = bbase[b];
    const unsigned long long* eb = ebuf + (size_t)b * CSR_CAP;
    ncnt[t] = 0; ncur[t] = 0;
    __syncthreads();
    for (int j = t; j < cntE; j += 256) {
        int ln = ((int)(eb[j] >> 32)) & 255;
        atomicAdd(&ncnt[ln], 1);
    }
    __syncthreads();
    int v = ncnt[t];
    nbase[t] = v;
    __syncthreads();
    for (int off = 1; off < 256; off <<= 1) {
        int add = (t >= off) ? nbase[t - off] : 0;
        __syncthreads();
        nbase[t] += add;
        __syncthreads();
    }
    int excl = nbase[t] - v;
    __syncthreads();
    nbase[t] = excl;
    __syncthreads();
    if (t < nodes) {
        rowptr[node0 + t] = base + excl;
        dinv[node0 + t] = rsqrtf((float)(v + 1));  // +1 self-loop
    }
    for (int j = t; j < cntE; j += 256) {
        unsigned long long p = eb[j];
        int s = (int)(p & 0xffffffffu);
        int ln = ((int)(p >> 32)) & 255;
        int r = atomicAdd(&ncur[ln], 1);
        stg[nbase[ln] + r] = s;
    }
    __syncthreads();
    for (int j = t; j < cntE; j += 256) csr_src[(size_t)base + j] = stg[j];
}

// ---------------- y4[n] = dinv[n] * {x0,x1,x2,0} ----------------
__global__ void k_y4(const float* __restrict__ x, const float* __restrict__ dinv,
                     float4* __restrict__ y4, int N) {
    int n = blockIdx.x * blockDim.x + threadIdx.x;
    if (n >= N) return;
    float dn = dinv[n];
    y4[n] = make_float4(dn * x[n * 3 + 0], dn * x[n * 3 + 1], dn * x[n * 3 + 2], 0.0f);
}

// ---------------- conv over pre-scaled x: agg3[n] = dn*(sum y4[s] + y4[n]) ---------
// 4 lanes per node; lane q = component q (comp 3 is the zero pad -> no branch).
__global__ __launch_bounds__(256) void k_agg3(
        const float* __restrict__ y, const int* __restrict__ csr_src,
        const int* __restrict__ rowptr, const float* __restrict__ dinv,
        float* __restrict__ agg3, int N) {
    int tid = blockIdx.x * blockDim.x + threadIdx.x;
    int n = tid >> 2, q = tid & 3;
    if (n >= N) return;
    int lane = threadIdx.x & 63;
    int base = lane & ~3;
    int beg = rowptr[n], end = rowptr[n + 1];
    float a0 = 0.f, a1 = 0.f, a2 = 0.f, a3 = 0.f;
    for (int c = beg; c < end; c += 4) {
        int myidx = csr_src[min(c + q, end - 1)];
        int m = min(4, end - c);
        if (m == 4) {
            int s0 = __shfl(myidx, base + 0);
            int s1 = __shfl(myidx, base + 1);
            int s2 = __shfl(myidx, base + 2);
            int s3 = __shfl(myidx, base + 3);
            a0 += y[s0 * 4 + q];
            a1 += y[s1 * 4 + q];
            a2 += y[s2 * 4 + q];
            a3 += y[s3 * 4 + q];
        } else {
            for (int j = 0; j < m; ++j) {
                int s = __shfl(myidx, base + j);
                a0 += y[s * 4 + q];
            }
        }
    }
    float total = (a0 + a1) + (a2 + a3) + y[n * 4 + q];  // + self
    agg3[(size_t)n * 4 + q] = dinv[n] * total;
}

// ---------------- Hs = dinv * relu(agg3 @ W1 + b1) ----------------
__global__ __launch_bounds__(256) void k_h1(
        const float* __restrict__ agg3, const float* __restrict__ W1,
        const float* __restrict__ b1, const float* __restrict__ dinv,
        float* __restrict__ Hs, int N) {
    int tid = blockIdx.x * blockDim.x + threadIdx.x;
    int n = tid >> 6, f = tid & 63;
    if (n >= N) return;
    float a0 = agg3[(size_t)n * 4 + 0];
    float a1 = agg3[(size_t)n * 4 + 1];
    float a2 = agg3[(size_t)n * 4 + 2];
    float v = a0 * W1[f] + a1 * W1[64 + f] + a2 * W1[128 + f] + b1[f];
    Hs[(size_t)n * 64 + f] = dinv[n] * fmaxf(v, 0.0f);
}

// ---------------- CSR gather (64 feats, pre-scaled rows): out = dn*(sum Hs + Hs[n]) -
// 16 lanes/node, shfl-broadcast index feed, 4-deep unroll (4 rows in flight/lane).
__global__ __launch_bounds__(256) void k_agg(
        const float* __restrict__ Hs, const int* __restrict__ csr_src,
        const int* __restrict__ rowptr, const float* __restrict__ dinv,
        float* __restrict__ out, int N) {
    int tid = blockIdx.x * blockDim.x + threadIdx.x;
    int n = tid >> 4, q = tid & 15;
    if (n >= N) return;
    int lane = threadIdx.x & 63;
    int base = lane & ~15;
    int beg = rowptr[n], end = rowptr[n + 1];
    const float4* Hp = (const float4*)Hs;
    float4 acc0 = make_float4(0.f, 0.f, 0.f, 0.f);
    float4 acc1 = make_float4(0.f, 0.f, 0.f, 0.f);
    float4 acc2 = make_float4(0.f, 0.f, 0.f, 0.f);
    float4 acc3 = make_float4(0.f, 0.f, 0.f, 0.f);
    for (int c = beg; c < end; c += 16) {
        int myidx = csr_src[min(c + q, end - 1)];
        int m = min(16, end - c);
        int j = 0;
        for (; j + 4 <= m; j += 4) {
            int s0 = __shfl(myidx, base + j + 0);
            int s1 = __shfl(myidx, base + j + 1);
            int s2 = __shfl(myidx, base + j + 2);
            int s3 = __shfl(myidx, base + j + 3);
            float4 h0 = Hp[(size_t)s0 * 16 + q];
            float4 h1 = Hp[(size_t)s1 * 16 + q];
            float4 h2 = Hp[(size_t)s2 * 16 + q];
            float4 h3 = Hp[(size_t)s3 * 16 + q];
            acc0.x += h0.x; acc0.y += h0.y; acc0.z += h0.z; acc0.w += h0.w;
            acc1.x += h1.x; acc1.y += h1.y; acc1.z += h1.z; acc1.w += h1.w;
            acc2.x += h2.x; acc2.y += h2.y; acc2.z += h2.z; acc2.w += h2.w;
            acc3.x += h3.x; acc3.y += h3.y; acc3.z += h3.z; acc3.w += h3.w;
        }
        for (; j < m; ++j) {
            int s = __shfl(myidx, base + j);
            float4 h = Hp[(size_t)s * 16 + q];
            acc0.x += h.x; acc0.y += h.y; acc0.z += h.z; acc0.w += h.w;
        }
    }
    float4 hs = Hp[(size_t)n * 16 + q];  // self (pre-scaled)
    float dn = dinv[n];
    float4 r;
    r.x = dn * ((acc0.x + acc1.x) + (acc2.x + acc3.x) + hs.x);
    r.y = dn * ((acc0.y + acc1.y) + (acc2.y + acc3.y) + hs.y);
    r.z = dn * ((acc0.z + acc1.z) + (acc2.z + acc3.z) + hs.z);
    r.w = dn * ((acc0.w + acc1.w) + (acc2.w + acc3.w) + hs.w);
    ((float4*)(out + (size_t)n * 64))[q] = r;
}

// ---------------- fused: relu(agg2 @ W2 + b2) . Wr -> hierarchical pool ------------
__global__ __launch_bounds__(256) void k_mmpool(
        const float* __restrict__ agg2, const float* __restrict__ W2,
        const float* __restrict__ b2, const float* __restrict__ Wr,
        const int* __restrict__ batch, float* __restrict__ gsum,
        float* __restrict__ gcnt, int N) {
    __shared__ float W2s[64 * 64];
    __shared__ float lsum[N_GRAPHS];
    __shared__ float lcnt[N_GRAPHS];
    int t = threadIdx.x;
    for (int i = t; i < 64 * 64; i += 256) W2s[i] = W2[i];
    if (t < N_GRAPHS) { lsum[t] = 0.f; lcnt[t] = 0.f; }
    __syncthreads();

    int lane = t & 63, wv = t >> 6;
    int chunk = (N + gridDim.x - 1) / gridDim.x;
    int n0 = blockIdx.x * chunk;
    int n1 = min(N, n0 + chunk);
    float wr = Wr[lane], bb = b2[lane];
    for (int n = n0 + wv; n < n1; n += 4) {
        float a = agg2[(size_t)n * 64 + lane];
        float acc = 0.0f;
#pragma unroll 16
        for (int k = 0; k < 64; ++k) {
            float ak = __shfl(a, k);
            acc += ak * W2s[k * 64 + lane];
        }
        float r = fmaxf(acc + bb, 0.0f) * wr;
        for (int off = 32; off > 0; off >>= 1) r += __shfl_down(r, off);
        if (lane == 0) {
            int g = batch[n];
            atomicAdd(&lsum[g], r);
            atomicAdd(&lcnt[g], 1.0f);
        }
    }
    __syncthreads();
    if (t < N_GRAPHS && lcnt[t] > 0.0f) {
        atomicAdd(&gsum[t], lsum[t]);
        atomicAdd(&gcnt[t], lcnt[t]);
    }
}

__global__ void k_out(const float* __restrict__ gsum, const float* __restrict__ gcnt,
                      const float* __restrict__ br, float* __restrict__ out) {
    int g = threadIdx.x;
    if (g < N_GRAPHS) out[g] = gsum[g] / fmaxf(gcnt[g], 1.0f) + br[0];
}

extern "C" void kernel_launch(void* const* d_in, const int* in_sizes, int n_in,
                              void* d_out, int out_size, void* d_ws, size_t ws_size,
                              hipStream_t stream) {
    const float* x     = (const float*)d_in[0];
    const int*   ei    = (const int*)d_in[1];   // [2, E]
    const int*   batch = (const int*)d_in[2];
    const float* W1    = (const float*)d_in[3];
    const float* b1    = (const float*)d_in[4];
    const float* W2    = (const float*)d_in[5];
    const float* b2    = (const float*)d_in[6];
    const float* Wr    = (const float*)d_in[7];
    const float* br    = (const float*)d_in[8];
    float* out = (float*)d_out;

    const int N = N_NODES, E = N_EDGES;
    const int* src = ei;
    const int* dst = ei + E;

    // workspace: ebuf (28.8 MB) aliases A+front-of-B (both dead until CSR built)
    char* w = (char*)d_ws;
    float* A       = (float*)w; w += (size_t)N * 64 * sizeof(float);  // agg3/agg2
    float* B       = (float*)w; w += (size_t)N * 64 * sizeof(float);  // Hs
    int*   csr_src = (int*)w;   w += (size_t)E * sizeof(int);
    float* dinv    = (float*)w; w += (size_t)N * sizeof(float);
    int*   rowptr  = (int*)w;   w += (size_t)(N + 1) * sizeof(int);
    int*   gcur    = (int*)w;   w += (size_t)NBUCK * sizeof(int);
    int*   bbase   = (int*)w;   w += (size_t)NBUCK * sizeof(int);
    float* gsum    = (float*)w; w += N_GRAPHS * sizeof(float);
    float* gcnt    = (float*)w; w += N_GRAPHS * sizeof(float);
    float4* y4     = (float4*)w; w += (size_t)N * sizeof(float4);
    unsigned long long* ebuf = (unsigned long long*)A;

    hipMemsetAsync(gcur, 0, (size_t)NBUCK * sizeof(int), stream);
    hipMemsetAsync(gsum, 0, N_GRAPHS * sizeof(float), stream);
    hipMemsetAsync(gcnt, 0, N_GRAPHS * sizeof(float), stream);

    // CSR build
    k_split<<<(E + TILE - 1) / TILE, 256, 0, stream>>>(src, dst, gcur, ebuf, E);
    k_bscan<<<1, 512, 0, stream>>>(gcur, bbase, rowptr);
    k_csr<<<NBUCK, 256, 0, stream>>>(ebuf, gcur, bbase, rowptr, dinv, csr_src, N);

    // layer 1: y4 = dinv*x, conv(y4), @W1+b1+relu (pre-scaled by dinv)
    k_y4<<<(N + 255) / 256, 256, 0, stream>>>(x, dinv, y4, N);
    k_agg3<<<(N * 4 + 255) / 256, 256, 0, stream>>>((const float*)y4, csr_src, rowptr, dinv, A, N);
    k_h1<<<(N * 64) / 256, 256, 0, stream>>>(A, W1, b1, dinv, B, N);

    // layer 2: conv(Hs), then fused @W2+b2+relu+.Wr+pool
    k_agg<<<(N * 16 + 255) / 256, 256, 0, stream>>>(B, csr_src, rowptr, dinv, A, N);
    k_mmpool<<<POOL_BLOCKS, 256, 0, stream>>>(A, W2, b2, Wr, batch, gsum, gcnt, N);

    k_out<<<1, 64, 0, stream>>>(gsum, gcnt, br, out);
}

// Round 8
// 345.819 us; speedup vs baseline: 19.0025x; 1.2374x over previous
//
#include <hip/hip_runtime.h>

#define N_NODES  100000
#define N_EDGES  3200000
#define N_GRAPHS 64
#define NBUCK 391          // ceil(100000 / 256)
#define TILE  4096         // edges per k_split block
#define CSR_CAP 9216       // fixed bucket capacity (mean 8192, sigma~90 -> 11 sigma)

// ---------------- P1: multisplit edges into 391 fixed-capacity dst-buckets ---------
__global__ __launch_bounds__(256) void k_split(
        const int* __restrict__ src, const int* __restrict__ dst,
        int* __restrict__ gcur, unsigned long long* __restrict__ ebuf, int E) {
    __shared__ int hist[512];
    __shared__ int scn[512];
    __shared__ int base[NBUCK];
    __shared__ int curs[NBUCK];
    __shared__ unsigned long long stg[TILE];  // 32 KB staging
    int t = threadIdx.x;
    for (int i = t; i < 512; i += 256) hist[i] = 0;
    __syncthreads();

    int e0 = blockIdx.x * TILE;
    for (int k = 0; k < TILE / 256; ++k) {
        int i = e0 + t + k * 256;
        if (i < E) atomicAdd(&hist[dst[i] >> 8], 1);
    }
    __syncthreads();
    scn[t] = hist[t]; scn[t + 256] = hist[t + 256];
    __syncthreads();
    for (int off = 1; off < 512; off <<= 1) {
        int v0 = (t >= off) ? scn[t - off] : 0;
        int v1 = (t + 256 >= off) ? scn[t + 256 - off] : 0;
        __syncthreads();
        scn[t] += v0; scn[t + 256] += v1;
        __syncthreads();
    }
    for (int b = t; b < NBUCK; b += 256) {
        int h = hist[b];
        if (h > 0) base[b] = atomicAdd(&gcur[b], h);
        curs[b] = 0;
    }
    __syncthreads();
    for (int k = 0; k < TILE / 256; ++k) {
        int i = e0 + t + k * 256;
        if (i < E) {
            int s = src[i], d = dst[i];
            int b = d >> 8;
            int r = atomicAdd(&curs[b], 1);
            int loff = scn[b] - hist[b];
            stg[loff + r] = ((unsigned long long)(unsigned)d << 32) | (unsigned)s;
        }
    }
    __syncthreads();
    int nvalid = min(TILE, E - e0);
    for (int j = t; j < nvalid; j += 256) {
        unsigned long long p = stg[j];
        int d = (int)(p >> 32);
        int b = d >> 8;
        int loff = scn[b] - hist[b];
        int pos = base[b] + (j - loff);
        if (pos < CSR_CAP) ebuf[(size_t)b * CSR_CAP + pos] = p;
    }
}

// ---------------- bucket totals -> global CSR bases (single block) ----------------
__global__ void k_bscan(const int* __restrict__ gcur, int* __restrict__ bbase,
                        int* __restrict__ rowptr) {
    __shared__ int tmp[512];
    int t = threadIdx.x;
    int v = (t < NBUCK) ? gcur[t] : 0;
    tmp[t] = v;
    __syncthreads();
    for (int off = 1; off < 512; off <<= 1) {
        int add = (t >= off) ? tmp[t - off] : 0;
        __syncthreads();
        tmp[t] += add;
        __syncthreads();
    }
    if (t < NBUCK) bbase[t] = tmp[t] - v;
    if (t == 0) rowptr[N_NODES] = N_EDGES;
}

// ---------------- P2: bucket -> per-node degree + rowptr + dinv + CSR --------------
__global__ __launch_bounds__(256) void k_csr(
        const unsigned long long* __restrict__ ebuf, const int* __restrict__ gcur,
        const int* __restrict__ bbase, int* __restrict__ rowptr,
        float* __restrict__ dinv, int* __restrict__ csr_src, int N) {
    __shared__ int ncnt[256];
    __shared__ int nbase[256];
    __shared__ int ncur[256];
    __shared__ int stg[CSR_CAP];  // 36 KB
    int b = blockIdx.x, t = threadIdx.x;
    int node0 = b << 8;
    int nodes = min(256, N - node0);
    int cntE = min(gcur[b], CSR_CAP);
    int base = bbase[b];
    const unsigned long long* eb = ebuf + (size_t)b * CSR_CAP;
    ncnt[t] = 0; ncur[t] = 0;
    __syncthreads();
    for (int j = t; j < cntE; j += 256) {
        int ln = ((int)(eb[j] >> 32)) & 255;
        atomicAdd(&ncnt[ln], 1);
    }
    __syncthreads();
    int v = ncnt[t];
    nbase[t] = v;
    __syncthreads();
    for (int off = 1; off < 256; off <<= 1) {
        int add = (t >= off) ? nbase[t - off] : 0;
        __syncthreads();
        nbase[t] += add;
        __syncthreads();
    }
    int excl = nbase[t] - v;
    __syncthreads();
    nbase[t] = excl;
    __syncthreads();
    if (t < nodes) {
        rowptr[node0 + t] = base + excl;
        dinv[node0 + t] = rsqrtf((float)(v + 1));  // +1 self-loop
    }
    for (int j = t; j < cntE; j += 256) {
        unsigned long long p = eb[j];
        int s = (int)(p & 0xffffffffu);
        int ln = ((int)(p >> 32)) & 255;
        int r = atomicAdd(&ncur[ln], 1);
        stg[nbase[ln] + r] = s;
    }
    __syncthreads();
    for (int j = t; j < cntE; j += 256) csr_src[(size_t)base + j] = stg[j];
}

// ---------------- y4[n] = dinv[n] * {x0,x1,x2,0} ----------------
__global__ void k_y4(const float* __restrict__ x, const float* __restrict__ dinv,
                     float4* __restrict__ y4, int N) {
    int n = blockIdx.x * blockDim.x + threadIdx.x;
    if (n >= N) return;
    float dn = dinv[n];
    y4[n] = make_float4(dn * x[n * 3 + 0], dn * x[n * 3 + 1], dn * x[n * 3 + 2], 0.0f);
}

// ---------------- conv over pre-scaled x: agg3[n] = dn*(sum y4[s] + y4[n]) ---------
__global__ __launch_bounds__(256) void k_agg3(
        const float* __restrict__ y, const int* __restrict__ csr_src,
        const int* __restrict__ rowptr, const float* __restrict__ dinv,
        float* __restrict__ agg3, int N) {
    int tid = blockIdx.x * blockDim.x + threadIdx.x;
    int n = tid >> 2, q = tid & 3;
    if (n >= N) return;
    int lane = threadIdx.x & 63;
    int base = lane & ~3;
    int beg = rowptr[n], end = rowptr[n + 1];
    float a0 = 0.f, a1 = 0.f, a2 = 0.f, a3 = 0.f;
    for (int c = beg; c < end; c += 4) {
        int myidx = csr_src[min(c + q, end - 1)];
        int m = min(4, end - c);
        if (m == 4) {
            int s0 = __shfl(myidx, base + 0);
            int s1 = __shfl(myidx, base + 1);
            int s2 = __shfl(myidx, base + 2);
            int s3 = __shfl(myidx, base + 3);
            a0 += y[s0 * 4 + q];
            a1 += y[s1 * 4 + q];
            a2 += y[s2 * 4 + q];
            a3 += y[s3 * 4 + q];
        } else {
            for (int j = 0; j < m; ++j) {
                int s = __shfl(myidx, base + j);
                a0 += y[s * 4 + q];
            }
        }
    }
    float total = (a0 + a1) + (a2 + a3) + y[n * 4 + q];  // + self
    agg3[(size_t)n * 4 + q] = dinv[n] * total;
}

// ---------------- Hs = dinv * relu(agg3 @ W1 + b1) ----------------
__global__ __launch_bounds__(256) void k_h1(
        const float* __restrict__ agg3, const float* __restrict__ W1,
        const float* __restrict__ b1, const float* __restrict__ dinv,
        float* __restrict__ Hs, int N) {
    int tid = blockIdx.x * blockDim.x + threadIdx.x;
    int n = tid >> 6, f = tid & 63;
    if (n >= N) return;
    float a0 = agg3[(size_t)n * 4 + 0];
    float a1 = agg3[(size_t)n * 4 + 1];
    float a2 = agg3[(size_t)n * 4 + 2];
    float v = a0 * W1[f] + a1 * W1[64 + f] + a2 * W1[128 + f] + b1[f];
    Hs[(size_t)n * 64 + f] = dinv[n] * fmaxf(v, 0.0f);
}

// ---------------- CSR gather (64 feats, pre-scaled rows) ----------------
__global__ __launch_bounds__(256) void k_agg(
        const float* __restrict__ Hs, const int* __restrict__ csr_src,
        const int* __restrict__ rowptr, const float* __restrict__ dinv,
        float* __restrict__ out, int N) {
    int tid = blockIdx.x * blockDim.x + threadIdx.x;
    int n = tid >> 4, q = tid & 15;
    if (n >= N) return;
    int lane = threadIdx.x & 63;
    int base = lane & ~15;
    int beg = rowptr[n], end = rowptr[n + 1];
    const float4* Hp = (const float4*)Hs;
    float4 acc0 = make_float4(0.f, 0.f, 0.f, 0.f);
    float4 acc1 = make_float4(0.f, 0.f, 0.f, 0.f);
    float4 acc2 = make_float4(0.f, 0.f, 0.f, 0.f);
    float4 acc3 = make_float4(0.f, 0.f, 0.f, 0.f);
    for (int c = beg; c < end; c += 16) {
        int myidx = csr_src[min(c + q, end - 1)];
        int m = min(16, end - c);
        int j = 0;
        for (; j + 4 <= m; j += 4) {
            int s0 = __shfl(myidx, base + j + 0);
            int s1 = __shfl(myidx, base + j + 1);
            int s2 = __shfl(myidx, base + j + 2);
            int s3 = __shfl(myidx, base + j + 3);
            float4 h0 = Hp[(size_t)s0 * 16 + q];
            float4 h1 = Hp[(size_t)s1 * 16 + q];
            float4 h2 = Hp[(size_t)s2 * 16 + q];
            float4 h3 = Hp[(size_t)s3 * 16 + q];
            acc0.x += h0.x; acc0.y += h0.y; acc0.z += h0.z; acc0.w += h0.w;
            acc1.x += h1.x; acc1.y += h1.y; acc1.z += h1.z; acc1.w += h1.w;
            acc2.x += h2.x; acc2.y += h2.y; acc2.z += h2.z; acc2.w += h2.w;
            acc3.x += h3.x; acc3.y += h3.y; acc3.z += h3.z; acc3.w += h3.w;
        }
        for (; j < m; ++j) {
            int s = __shfl(myidx, base + j);
            float4 h = Hp[(size_t)s * 16 + q];
            acc0.x += h.x; acc0.y += h.y; acc0.z += h.z; acc0.w += h.w;
        }
    }
    float4 hs = Hp[(size_t)n * 16 + q];  // self (pre-scaled)
    float dn = dinv[n];
    float4 r;
    r.x = dn * ((acc0.x + acc1.x) + (acc2.x + acc3.x) + hs.x);
    r.y = dn * ((acc0.y + acc1.y) + (acc2.y + acc3.y) + hs.y);
    r.z = dn * ((acc0.z + acc1.z) + (acc2.z + acc3.z) + hs.z);
    r.w = dn * ((acc0.w + acc1.w) + (acc2.w + acc3.w) + hs.w);
    ((float4*)(out + (size_t)n * 64))[q] = r;
}

// ---------------- tiled GEMM + fused pool ----------------
// Block = 128 nodes (2 tiles of 64) x 64 feats. Thread = 4 nodes x 4 feats,
// 16 independent accumulators. W2 in LDS (float4 [k][f4]); A rows via global
// float4 broadcast loads. Epilogue: +b2, relu, .Wr, shfl-reduce over the 16
// feature lanes, LDS per-graph table, one global atomic per graph per block.
__device__ __forceinline__ void fma4(float4& c, float s, const float4& w) {
    c.x += s * w.x; c.y += s * w.y; c.z += s * w.z; c.w += s * w.w;
}

__global__ __launch_bounds__(256) void k_mmpool(
        const float4* __restrict__ A4, const float4* __restrict__ W2v,
        const float* __restrict__ b2, const float* __restrict__ Wr,
        const int* __restrict__ batch, float* __restrict__ gsum,
        float* __restrict__ gcnt, int N) {
    __shared__ float4 W2s[1024];  // [k][f4], 16 KB
    __shared__ float lsum[N_GRAPHS];
    __shared__ float lcnt[N_GRAPHS];
    int t = threadIdx.x;
    for (int i = t; i < 1024; i += 256) W2s[i] = W2v[i];
    if (t < N_GRAPHS) { lsum[t] = 0.f; lcnt[t] = 0.f; }
    __syncthreads();

    int f4 = t & 15;   // features 4*f4 .. 4*f4+3
    int ng = t >> 4;   // node group 0..15 (lanes 16g..16g+15 share ng)
    float4 bb = ((const float4*)b2)[f4];
    float4 wr = ((const float4*)Wr)[f4];
    int base = blockIdx.x * 128;

    for (int tile = 0; tile < 2; ++tile) {
        int n0 = base + tile * 64 + ng * 4;
        int m0 = min(n0 + 0, N - 1), m1 = min(n0 + 1, N - 1);
        int m2 = min(n0 + 2, N - 1), m3 = min(n0 + 3, N - 1);
        const float4* r0 = A4 + (size_t)m0 * 16;
        const float4* r1 = A4 + (size_t)m1 * 16;
        const float4* r2 = A4 + (size_t)m2 * 16;
        const float4* r3 = A4 + (size_t)m3 * 16;
        float4 c0 = make_float4(0.f, 0.f, 0.f, 0.f);
        float4 c1 = make_float4(0.f, 0.f, 0.f, 0.f);
        float4 c2 = make_float4(0.f, 0.f, 0.f, 0.f);
        float4 c3 = make_float4(0.f, 0.f, 0.f, 0.f);
#pragma unroll 4
        for (int ks = 0; ks < 16; ++ks) {  // k = 4*ks .. 4*ks+3
            float4 a0 = r0[ks], a1 = r1[ks], a2 = r2[ks], a3 = r3[ks];
            float4 w0 = W2s[(4 * ks + 0) * 16 + f4];
            float4 w1 = W2s[(4 * ks + 1) * 16 + f4];
            float4 w2 = W2s[(4 * ks + 2) * 16 + f4];
            float4 w3 = W2s[(4 * ks + 3) * 16 + f4];
            fma4(c0, a0.x, w0); fma4(c0, a0.y, w1); fma4(c0, a0.z, w2); fma4(c0, a0.w, w3);
            fma4(c1, a1.x, w0); fma4(c1, a1.y, w1); fma4(c1, a1.z, w2); fma4(c1, a1.w, w3);
            fma4(c2, a2.x, w0); fma4(c2, a2.y, w1); fma4(c2, a2.z, w2); fma4(c2, a2.w, w3);
            fma4(c3, a3.x, w0); fma4(c3, a3.y, w1); fma4(c3, a3.z, w2); fma4(c3, a3.w, w3);
        }
        // epilogue: p_i = sum_j relu(c_i[j]+b2)*Wr
        float p0 = fmaxf(c0.x + bb.x, 0.f) * wr.x + fmaxf(c0.y + bb.y, 0.f) * wr.y +
                   fmaxf(c0.z + bb.z, 0.f) * wr.z + fmaxf(c0.w + bb.w, 0.f) * wr.w;
        float p1 = fmaxf(c1.x + bb.x, 0.f) * wr.x + fmaxf(c1.y + bb.y, 0.f) * wr.y +
                   fmaxf(c1.z + bb.z, 0.f) * wr.z + fmaxf(c1.w + bb.w, 0.f) * wr.w;
        float p2 = fmaxf(c2.x + bb.x, 0.f) * wr.x + fmaxf(c2.y + bb.y, 0.f) * wr.y +
                   fmaxf(c2.z + bb.z, 0.f) * wr.z + fmaxf(c2.w + bb.w, 0.f) * wr.w;
        float p3 = fmaxf(c3.x + bb.x, 0.f) * wr.x + fmaxf(c3.y + bb.y, 0.f) * wr.y +
                   fmaxf(c3.z + bb.z, 0.f) * wr.z + fmaxf(c3.w + bb.w, 0.f) * wr.w;
        // reduce over the 16 feature lanes
        for (int off = 8; off > 0; off >>= 1) {
            p0 += __shfl_down(p0, off);
            p1 += __shfl_down(p1, off);
            p2 += __shfl_down(p2, off);
            p3 += __shfl_down(p3, off);
        }
        if (f4 == 0) {
            if (n0 + 0 < N) { int g = batch[n0 + 0]; atomicAdd(&lsum[g], p0); atomicAdd(&lcnt[g], 1.f); }
            if (n0 + 1 < N) { int g = batch[n0 + 1]; atomicAdd(&lsum[g], p1); atomicAdd(&lcnt[g], 1.f); }
            if (n0 + 2 < N) { int g = batch[n0 + 2]; atomicAdd(&lsum[g], p2); atomicAdd(&lcnt[g], 1.f); }
            if (n0 + 3 < N) { int g = batch[n0 + 3]; atomicAdd(&lsum[g], p3); atomicAdd(&lcnt[g], 1.f); }
        }
    }
    __syncthreads();
    if (t < N_GRAPHS && lcnt[t] > 0.0f) {
        atomicAdd(&gsum[t], lsum[t]);
        atomicAdd(&gcnt[t], lcnt[t]);
    }
}

__global__ void k_out(const float* __restrict__ gsum, const float* __restrict__ gcnt,
                      const float* __restrict__ br, float* __restrict__ out) {
    int g = threadIdx.x;
    if (g < N_GRAPHS) out[g] = gsum[g] / fmaxf(gcnt[g], 1.0f) + br[0];
}

extern "C" void kernel_launch(void* const* d_in, const int* in_sizes, int n_in,
                              void* d_out, int out_size, void* d_ws, size_t ws_size,
                              hipStream_t stream) {
    const float* x     = (const float*)d_in[0];
    const int*   ei    = (const int*)d_in[1];   // [2, E]
    const int*   batch = (const int*)d_in[2];
    const float* W1    = (const float*)d_in[3];
    const float* b1    = (const float*)d_in[4];
    const float* W2    = (const float*)d_in[5];
    const float* b2    = (const float*)d_in[6];
    const float* Wr    = (const float*)d_in[7];
    const float* br    = (const float*)d_in[8];
    float* out = (float*)d_out;

    const int N = N_NODES, E = N_EDGES;
    const int* src = ei;
    const int* dst = ei + E;

    // workspace: ebuf (28.8 MB) aliases A+front-of-B (both dead until CSR built)
    char* w = (char*)d_ws;
    float* A       = (float*)w; w += (size_t)N * 64 * sizeof(float);  // agg3/agg2
    float* B       = (float*)w; w += (size_t)N * 64 * sizeof(float);  // Hs
    int*   csr_src = (int*)w;   w += (size_t)E * sizeof(int);
    float* dinv    = (float*)w; w += (size_t)N * sizeof(float);
    int*   rowptr  = (int*)w;   w += (size_t)(N + 1) * sizeof(int);
    int*   gcur    = (int*)w;   w += (size_t)NBUCK * sizeof(int);
    int*   bbase   = (int*)w;   w += (size_t)NBUCK * sizeof(int);
    float* gsum    = (float*)w; w += N_GRAPHS * sizeof(float);
    float* gcnt    = (float*)w; w += N_GRAPHS * sizeof(float);
    float4* y4     = (float4*)w; w += (size_t)N * sizeof(float4);
    unsigned long long* ebuf = (unsigned long long*)A;

    hipMemsetAsync(gcur, 0, (size_t)NBUCK * sizeof(int), stream);
    hipMemsetAsync(gsum, 0, N_GRAPHS * sizeof(float), stream);
    hipMemsetAsync(gcnt, 0, N_GRAPHS * sizeof(float), stream);

    // CSR build
    k_split<<<(E + TILE - 1) / TILE, 256, 0, stream>>>(src, dst, gcur, ebuf, E);
    k_bscan<<<1, 512, 0, stream>>>(gcur, bbase, rowptr);
    k_csr<<<NBUCK, 256, 0, stream>>>(ebuf, gcur, bbase, rowptr, dinv, csr_src, N);

    // layer 1: y4 = dinv*x, conv(y4), @W1+b1+relu (pre-scaled by dinv)
    k_y4<<<(N + 255) / 256, 256, 0, stream>>>(x, dinv, y4, N);
    k_agg3<<<(N * 4 + 255) / 256, 256, 0, stream>>>((const float*)y4, csr_src, rowptr, dinv, A, N);
    k_h1<<<(N * 64) / 256, 256, 0, stream>>>(A, W1, b1, dinv, B, N);

    // layer 2: conv(Hs), then fused tiled-GEMM @W2+b2+relu+.Wr+pool
    k_agg<<<(N * 16 + 255) / 256, 256, 0, stream>>>(B, csr_src, rowptr, dinv, A, N);
    k_mmpool<<<(N + 127) / 128, 256, 0, stream>>>((const float4*)A, (const float4*)W2,
                                                  b2, Wr, batch, gsum, gcnt, N);

    k_out<<<1, 64, 0, stream>>>(gsum, gcnt, br, out);
}

// Round 9
// 281.486 us; speedup vs baseline: 23.3455x; 1.2285x over previous
//
#include <hip/hip_runtime.h>

#define N_NODES  100000
#define N_EDGES  3200000
#define N_GRAPHS 64
#define NBUCK 391          // ceil(100000 / 256)
#define TILE  4096         // edges per k_split block
#define CSR_CAP 9216       // fixed bucket capacity (mean 8192, sigma~90 -> 11 sigma)

__device__ __forceinline__ unsigned bf16rne(float f) {       // RNE fp32->bf16 bits
    unsigned u = __float_as_uint(f);
    return (u + 0x7FFFu + ((u >> 16) & 1u)) >> 16;
}
__device__ __forceinline__ float bf2f(unsigned short h) {
    return __uint_as_float((unsigned)h << 16);
}

// ---------------- P1: multisplit edges into 391 fixed-capacity dst-buckets ---------
// ebuf entry: (dst&255)<<24 | src   (src < 2^17)
__global__ __launch_bounds__(256) void k_split(
        const int* __restrict__ src, const int* __restrict__ dst,
        int* __restrict__ gcur, unsigned int* __restrict__ ebuf, int E) {
    __shared__ int hist[512];
    __shared__ int scn[512];
    __shared__ int base[NBUCK];
    __shared__ int curs[NBUCK];
    __shared__ unsigned int stg[TILE];    // 16 KB staging (packed)
    __shared__ unsigned short bkt[TILE];  // 8 KB bucket id per slot
    int t = threadIdx.x;
    for (int i = t; i < 512; i += 256) hist[i] = 0;
    __syncthreads();

    int e0 = blockIdx.x * TILE;
    for (int k = 0; k < TILE / 256; ++k) {
        int i = e0 + t + k * 256;
        if (i < E) atomicAdd(&hist[dst[i] >> 8], 1);
    }
    __syncthreads();
    scn[t] = hist[t]; scn[t + 256] = hist[t + 256];
    __syncthreads();
    for (int off = 1; off < 512; off <<= 1) {
        int v0 = (t >= off) ? scn[t - off] : 0;
        int v1 = (t + 256 >= off) ? scn[t + 256 - off] : 0;
        __syncthreads();
        scn[t] += v0; scn[t + 256] += v1;
        __syncthreads();
    }
    for (int b = t; b < NBUCK; b += 256) {
        int h = hist[b];
        if (h > 0) base[b] = atomicAdd(&gcur[b], h);
        curs[b] = 0;
    }
    __syncthreads();
    for (int k = 0; k < TILE / 256; ++k) {
        int i = e0 + t + k * 256;
        if (i < E) {
            int s = src[i], d = dst[i];
            int b = d >> 8;
            int r = atomicAdd(&curs[b], 1);
            int pos = scn[b] - hist[b] + r;
            stg[pos] = ((unsigned)(d & 255) << 24) | (unsigned)s;
            bkt[pos] = (unsigned short)b;
        }
    }
    __syncthreads();
    int nvalid = min(TILE, E - e0);
    for (int j = t; j < nvalid; j += 256) {
        unsigned p = stg[j];
        int b = bkt[j];
        int loff = scn[b] - hist[b];
        int pos = base[b] + (j - loff);
        if (pos < CSR_CAP) ebuf[(size_t)b * CSR_CAP + pos] = p;
    }
}

// ---------------- bucket totals -> global CSR bases (single block) ----------------
__global__ void k_bscan(const int* __restrict__ gcur, int* __restrict__ bbase,
                        int* __restrict__ rowptr) {
    __shared__ int tmp[512];
    int t = threadIdx.x;
    int v = (t < NBUCK) ? gcur[t] : 0;
    tmp[t] = v;
    __syncthreads();
    for (int off = 1; off < 512; off <<= 1) {
        int add = (t >= off) ? tmp[t - off] : 0;
        __syncthreads();
        tmp[t] += add;
        __syncthreads();
    }
    if (t < NBUCK) bbase[t] = tmp[t] - v;
    if (t == 0) rowptr[N_NODES] = N_EDGES;
}

// ---------------- P2: bucket -> per-node degree + rowptr + dinv + CSR --------------
__global__ __launch_bounds__(256) void k_csr(
        const unsigned int* __restrict__ ebuf, const int* __restrict__ gcur,
        const int* __restrict__ bbase, int* __restrict__ rowptr,
        float* __restrict__ dinv, int* __restrict__ csr_src, int N) {
    __shared__ int ncnt[256];
    __shared__ int nbase[256];
    __shared__ int ncur[256];
    __shared__ int stg[CSR_CAP];  // 36 KB
    int b = blockIdx.x, t = threadIdx.x;
    int node0 = b << 8;
    int nodes = min(256, N - node0);
    int cntE = min(gcur[b], CSR_CAP);
    int base = bbase[b];
    const unsigned int* eb = ebuf + (size_t)b * CSR_CAP;
    ncnt[t] = 0; ncur[t] = 0;
    __syncthreads();
    for (int j = t; j < cntE; j += 256) {
        int ln = (int)(eb[j] >> 24);
        atomicAdd(&ncnt[ln], 1);
    }
    __syncthreads();
    int v = ncnt[t];
    nbase[t] = v;
    __syncthreads();
    for (int off = 1; off < 256; off <<= 1) {
        int add = (t >= off) ? nbase[t - off] : 0;
        __syncthreads();
        nbase[t] += add;
        __syncthreads();
    }
    int excl = nbase[t] - v;
    __syncthreads();
    nbase[t] = excl;
    __syncthreads();
    if (t < nodes) {
        rowptr[node0 + t] = base + excl;
        dinv[node0 + t] = rsqrtf((float)(v + 1));  // +1 self-loop
    }
    for (int j = t; j < cntE; j += 256) {
        unsigned p = eb[j];
        int s = (int)(p & 0xFFFFFFu);
        int ln = (int)(p >> 24);
        int r = atomicAdd(&ncur[ln], 1);
        stg[nbase[ln] + r] = s;
    }
    __syncthreads();
    for (int j = t; j < cntE; j += 256) csr_src[(size_t)base + j] = stg[j];
}

// ---------------- y4[n] = dinv[n] * {x0,x1,x2,0} ----------------
__global__ void k_y4(const float* __restrict__ x, const float* __restrict__ dinv,
                     float4* __restrict__ y4, int N) {
    int n = blockIdx.x * blockDim.x + threadIdx.x;
    if (n >= N) return;
    float dn = dinv[n];
    y4[n] = make_float4(dn * x[n * 3 + 0], dn * x[n * 3 + 1], dn * x[n * 3 + 2], 0.0f);
}

// ---------------- conv over pre-scaled x: agg3[n] = dn*(sum y4[s] + y4[n]) ---------
__global__ __launch_bounds__(256) void k_agg3(
        const float* __restrict__ y, const int* __restrict__ csr_src,
        const int* __restrict__ rowptr, const float* __restrict__ dinv,
        float* __restrict__ agg3, int N) {
    int tid = blockIdx.x * blockDim.x + threadIdx.x;
    int n = tid >> 2, q = tid & 3;
    if (n >= N) return;
    int lane = threadIdx.x & 63;
    int base = lane & ~3;
    int beg = rowptr[n], end = rowptr[n + 1];
    float a0 = 0.f, a1 = 0.f, a2 = 0.f, a3 = 0.f;
    for (int c = beg; c < end; c += 4) {
        int myidx = csr_src[min(c + q, end - 1)];
        int m = min(4, end - c);
        if (m == 4) {
            int s0 = __shfl(myidx, base + 0);
            int s1 = __shfl(myidx, base + 1);
            int s2 = __shfl(myidx, base + 2);
            int s3 = __shfl(myidx, base + 3);
            a0 += y[s0 * 4 + q];
            a1 += y[s1 * 4 + q];
            a2 += y[s2 * 4 + q];
            a3 += y[s3 * 4 + q];
        } else {
            for (int j = 0; j < m; ++j) {
                int s = __shfl(myidx, base + j);
                a0 += y[s * 4 + q];
            }
        }
    }
    float total = (a0 + a1) + (a2 + a3) + y[n * 4 + q];  // + self
    agg3[(size_t)n * 4 + q] = dinv[n] * total;
}

// ---------------- Hs(bf16) = dinv * relu(agg3 @ W1 + b1); 2 feats/thread -----------
__global__ __launch_bounds__(256) void k_h1(
        const float* __restrict__ agg3, const float* __restrict__ W1,
        const float* __restrict__ b1, const float* __restrict__ dinv,
        unsigned int* __restrict__ Hs2, int N) {
    int tid = blockIdx.x * blockDim.x + threadIdx.x;
    int n = tid >> 5, f = (tid & 31) * 2;
    if (n >= N) return;
    float a0 = agg3[(size_t)n * 4 + 0];
    float a1 = agg3[(size_t)n * 4 + 1];
    float a2 = agg3[(size_t)n * 4 + 2];
    float dn = dinv[n];
    float v0 = dn * fmaxf(a0 * W1[f]     + a1 * W1[64 + f]     + a2 * W1[128 + f]     + b1[f],     0.0f);
    float v1 = dn * fmaxf(a0 * W1[f + 1] + a1 * W1[64 + f + 1] + a2 * W1[128 + f + 1] + b1[f + 1], 0.0f);
    Hs2[(size_t)n * 32 + (f >> 1)] = bf16rne(v0) | (bf16rne(v1) << 16);
}

// ---------------- CSR gather (64 feats, bf16 pre-scaled rows, 128 B/row) -----------
// 16 lanes/node, shfl index feed, 4-deep unroll; fp32 accumulate; fp32 out.
__global__ __launch_bounds__(256) void k_agg(
        const unsigned short* __restrict__ Hs, const int* __restrict__ csr_src,
        const int* __restrict__ rowptr, const float* __restrict__ dinv,
        float* __restrict__ out, int N) {
    int tid = blockIdx.x * blockDim.x + threadIdx.x;
    int n = tid >> 4, q = tid & 15;
    if (n >= N) return;
    int lane = threadIdx.x & 63;
    int base = lane & ~15;
    int beg = rowptr[n], end = rowptr[n + 1];
    const ushort4* Hp = (const ushort4*)Hs;  // row = 16 x ushort4
    float4 acc0 = make_float4(0.f, 0.f, 0.f, 0.f);
    float4 acc1 = make_float4(0.f, 0.f, 0.f, 0.f);
    float4 acc2 = make_float4(0.f, 0.f, 0.f, 0.f);
    float4 acc3 = make_float4(0.f, 0.f, 0.f, 0.f);
    for (int c = beg; c < end; c += 16) {
        int myidx = csr_src[min(c + q, end - 1)];
        int m = min(16, end - c);
        int j = 0;
        for (; j + 4 <= m; j += 4) {
            int s0 = __shfl(myidx, base + j + 0);
            int s1 = __shfl(myidx, base + j + 1);
            int s2 = __shfl(myidx, base + j + 2);
            int s3 = __shfl(myidx, base + j + 3);
            ushort4 h0 = Hp[(size_t)s0 * 16 + q];
            ushort4 h1 = Hp[(size_t)s1 * 16 + q];
            ushort4 h2 = Hp[(size_t)s2 * 16 + q];
            ushort4 h3 = Hp[(size_t)s3 * 16 + q];
            acc0.x += bf2f(h0.x); acc0.y += bf2f(h0.y); acc0.z += bf2f(h0.z); acc0.w += bf2f(h0.w);
            acc1.x += bf2f(h1.x); acc1.y += bf2f(h1.y); acc1.z += bf2f(h1.z); acc1.w += bf2f(h1.w);
            acc2.x += bf2f(h2.x); acc2.y += bf2f(h2.y); acc2.z += bf2f(h2.z); acc2.w += bf2f(h2.w);
            acc3.x += bf2f(h3.x); acc3.y += bf2f(h3.y); acc3.z += bf2f(h3.z); acc3.w += bf2f(h3.w);
        }
        for (; j < m; ++j) {
            int s = __shfl(myidx, base + j);
            ushort4 h = Hp[(size_t)s * 16 + q];
            acc0.x += bf2f(h.x); acc0.y += bf2f(h.y); acc0.z += bf2f(h.z); acc0.w += bf2f(h.w);
        }
    }
    ushort4 hs = Hp[(size_t)n * 16 + q];  // self (pre-scaled)
    float dn = dinv[n];
    float4 r;
    r.x = dn * ((acc0.x + acc1.x) + (acc2.x + acc3.x) + bf2f(hs.x));
    r.y = dn * ((acc0.y + acc1.y) + (acc2.y + acc3.y) + bf2f(hs.y));
    r.z = dn * ((acc0.z + acc1.z) + (acc2.z + acc3.z) + bf2f(hs.z));
    r.w = dn * ((acc0.w + acc1.w) + (acc2.w + acc3.w) + bf2f(hs.w));
    ((float4*)(out + (size_t)n * 64))[q] = r;
}

// ---------------- tiled GEMM + fused pool ----------------
__device__ __forceinline__ void fma4(float4& c, float s, const float4& w) {
    c.x += s * w.x; c.y += s * w.y; c.z += s * w.z; c.w += s * w.w;
}

__global__ __launch_bounds__(256) void k_mmpool(
        const float4* __restrict__ A4, const float4* __restrict__ W2v,
        const float* __restrict__ b2, const float* __restrict__ Wr,
        const int* __restrict__ batch, float* __restrict__ gsum,
        float* __restrict__ gcnt, int N) {
    __shared__ float4 W2s[1024];  // [k][f4], 16 KB
    __shared__ float lsum[N_GRAPHS];
    __shared__ float lcnt[N_GRAPHS];
    int t = threadIdx.x;
    for (int i = t; i < 1024; i += 256) W2s[i] = W2v[i];
    if (t < N_GRAPHS) { lsum[t] = 0.f; lcnt[t] = 0.f; }
    __syncthreads();

    int f4 = t & 15;
    int ng = t >> 4;
    float4 bb = ((const float4*)b2)[f4];
    float4 wr = ((const float4*)Wr)[f4];
    int base = blockIdx.x * 128;

    for (int tile = 0; tile < 2; ++tile) {
        int n0 = base + tile * 64 + ng * 4;
        int m0 = min(n0 + 0, N - 1), m1 = min(n0 + 1, N - 1);
        int m2 = min(n0 + 2, N - 1), m3 = min(n0 + 3, N - 1);
        const float4* r0 = A4 + (size_t)m0 * 16;
        const float4* r1 = A4 + (size_t)m1 * 16;
        const float4* r2 = A4 + (size_t)m2 * 16;
        const float4* r3 = A4 + (size_t)m3 * 16;
        float4 c0 = make_float4(0.f, 0.f, 0.f, 0.f);
        float4 c1 = make_float4(0.f, 0.f, 0.f, 0.f);
        float4 c2 = make_float4(0.f, 0.f, 0.f, 0.f);
        float4 c3 = make_float4(0.f, 0.f, 0.f, 0.f);
#pragma unroll 4
        for (int ks = 0; ks < 16; ++ks) {
            float4 a0 = r0[ks], a1 = r1[ks], a2 = r2[ks], a3 = r3[ks];
            float4 w0 = W2s[(4 * ks + 0) * 16 + f4];
            float4 w1 = W2s[(4 * ks + 1) * 16 + f4];
            float4 w2 = W2s[(4 * ks + 2) * 16 + f4];
            float4 w3 = W2s[(4 * ks + 3) * 16 + f4];
            fma4(c0, a0.x, w0); fma4(c0, a0.y, w1); fma4(c0, a0.z, w2); fma4(c0, a0.w, w3);
            fma4(c1, a1.x, w0); fma4(c1, a1.y, w1); fma4(c1, a1.z, w2); fma4(c1, a1.w, w3);
            fma4(c2, a2.x, w0); fma4(c2, a2.y, w1); fma4(c2, a2.z, w2); fma4(c2, a2.w, w3);
            fma4(c3, a3.x, w0); fma4(c3, a3.y, w1); fma4(c3, a3.z, w2); fma4(c3, a3.w, w3);
        }
        float p0 = fmaxf(c0.x + bb.x, 0.f) * wr.x + fmaxf(c0.y + bb.y, 0.f) * wr.y +
                   fmaxf(c0.z + bb.z, 0.f) * wr.z + fmaxf(c0.w + bb.w, 0.f) * wr.w;
        float p1 = fmaxf(c1.x + bb.x, 0.f) * wr.x + fmaxf(c1.y + bb.y, 0.f) * wr.y +
                   fmaxf(c1.z + bb.z, 0.f) * wr.z + fmaxf(c1.w + bb.w, 0.f) * wr.w;
        float p2 = fmaxf(c2.x + bb.x, 0.f) * wr.x + fmaxf(c2.y + bb.y, 0.f) * wr.y +
                   fmaxf(c2.z + bb.z, 0.f) * wr.z + fmaxf(c2.w + bb.w, 0.f) * wr.w;
        float p3 = fmaxf(c3.x + bb.x, 0.f) * wr.x + fmaxf(c3.y + bb.y, 0.f) * wr.y +
                   fmaxf(c3.z + bb.z, 0.f) * wr.z + fmaxf(c3.w + bb.w, 0.f) * wr.w;
        for (int off = 8; off > 0; off >>= 1) {
            p0 += __shfl_down(p0, off);
            p1 += __shfl_down(p1, off);
            p2 += __shfl_down(p2, off);
            p3 += __shfl_down(p3, off);
        }
        if (f4 == 0) {
            if (n0 + 0 < N) { int g = batch[n0 + 0]; atomicAdd(&lsum[g], p0); atomicAdd(&lcnt[g], 1.f); }
            if (n0 + 1 < N) { int g = batch[n0 + 1]; atomicAdd(&lsum[g], p1); atomicAdd(&lcnt[g], 1.f); }
            if (n0 + 2 < N) { int g = batch[n0 + 2]; atomicAdd(&lsum[g], p2); atomicAdd(&lcnt[g], 1.f); }
            if (n0 + 3 < N) { int g = batch[n0 + 3]; atomicAdd(&lsum[g], p3); atomicAdd(&lcnt[g], 1.f); }
        }
    }
    __syncthreads();
    if (t < N_GRAPHS && lcnt[t] > 0.0f) {
        atomicAdd(&gsum[t], lsum[t]);
        atomicAdd(&gcnt[t], lcnt[t]);
    }
}

__global__ void k_out(const float* __restrict__ gsum, const float* __restrict__ gcnt,
                      const float* __restrict__ br, float* __restrict__ out) {
    int g = threadIdx.x;
    if (g < N_GRAPHS) out[g] = gsum[g] / fmaxf(gcnt[g], 1.0f) + br[0];
}

extern "C" void kernel_launch(void* const* d_in, const int* in_sizes, int n_in,
                              void* d_out, int out_size, void* d_ws, size_t ws_size,
                              hipStream_t stream) {
    const float* x     = (const float*)d_in[0];
    const int*   ei    = (const int*)d_in[1];   // [2, E]
    const int*   batch = (const int*)d_in[2];
    const float* W1    = (const float*)d_in[3];
    const float* b1    = (const float*)d_in[4];
    const float* W2    = (const float*)d_in[5];
    const float* b2    = (const float*)d_in[6];
    const float* Wr    = (const float*)d_in[7];
    const float* br    = (const float*)d_in[8];
    float* out = (float*)d_out;

    const int N = N_NODES, E = N_EDGES;
    const int* src = ei;
    const int* dst = ei + E;

    // workspace: ebuf (14.4 MB, uint32) aliases A (25.6 MB; dead until CSR built)
    char* w = (char*)d_ws;
    float* A        = (float*)w; w += (size_t)N * 64 * sizeof(float);   // agg3/agg2
    unsigned short* Hs = (unsigned short*)w; w += (size_t)N * 64 * sizeof(unsigned short);  // bf16 Hs
    int*   csr_src  = (int*)w;   w += (size_t)E * sizeof(int);
    float* dinv     = (float*)w; w += (size_t)N * sizeof(float);
    int*   rowptr   = (int*)w;   w += (size_t)(N + 1) * sizeof(int);
    int*   gcur     = (int*)w;   w += (size_t)NBUCK * sizeof(int);
    int*   bbase    = (int*)w;   w += (size_t)NBUCK * sizeof(int);
    float* gsum     = (float*)w; w += N_GRAPHS * sizeof(float);
    float* gcnt     = (float*)w; w += N_GRAPHS * sizeof(float);
    float4* y4      = (float4*)w; w += (size_t)N * sizeof(float4);
    unsigned int* ebuf = (unsigned int*)A;

    hipMemsetAsync(gcur, 0, (size_t)NBUCK * sizeof(int), stream);
    hipMemsetAsync(gsum, 0, N_GRAPHS * sizeof(float), stream);
    hipMemsetAsync(gcnt, 0, N_GRAPHS * sizeof(float), stream);

    // CSR build
    k_split<<<(E + TILE - 1) / TILE, 256, 0, stream>>>(src, dst, gcur, ebuf, E);
    k_bscan<<<1, 512, 0, stream>>>(gcur, bbase, rowptr);
    k_csr<<<NBUCK, 256, 0, stream>>>(ebuf, gcur, bbase, rowptr, dinv, csr_src, N);

    // layer 1: y4 = dinv*x, conv(y4), Hs = bf16(dinv*relu(@W1+b1))
    k_y4<<<(N + 255) / 256, 256, 0, stream>>>(x, dinv, y4, N);
    k_agg3<<<(N * 4 + 255) / 256, 256, 0, stream>>>((const float*)y4, csr_src, rowptr, dinv, A, N);
    k_h1<<<(N * 32 + 255) / 256, 256, 0, stream>>>(A, W1, b1, dinv, (unsigned int*)Hs, N);

    // layer 2: conv(Hs bf16) -> fp32 agg2, then fused tiled-GEMM @W2+b2+relu+.Wr+pool
    k_agg<<<(N * 16 + 255) / 256, 256, 0, stream>>>(Hs, csr_src, rowptr, dinv, A, N);
    k_mmpool<<<(N + 127) / 128, 256, 0, stream>>>((const float4*)A, (const float4*)W2,
                                                  b2, Wr, batch, gsum, gcnt, N);

    k_out<<<1, 64, 0, stream>>>(gsum, gcnt, br, out);
}